// Round 13
// baseline (343.605 us; speedup 1.0000x reference)
//
#include <hip/hip_runtime.h>
#include <hip/hip_bf16.h>
#include <stdint.h>

#define DEV static __device__ __forceinline__

typedef float f32x4 __attribute__((ext_vector_type(4)));
typedef __bf16 bf16x8 __attribute__((ext_vector_type(8)));
typedef unsigned short u16x8 __attribute__((ext_vector_type(8)));
typedef unsigned short u16x4 __attribute__((ext_vector_type(4)));
typedef uint32_t u32x4 __attribute__((ext_vector_type(4)));
typedef unsigned short u16;

#define B_ 2
#define L_ 2048
#define D_MODEL_ 1024
#define H_ 16
#define DH_ 64

// shift in base-2 score domain: 8 (base-e) * log2(e)
#define SHIFT2 11.5415603f

DEV u16 f2bf(float f) {
  union { float f; uint32_t u; } v; v.f = f;
  uint32_t r = v.u + 0x7FFFu + ((v.u >> 16) & 1u);  // RNE
  return (u16)(r >> 16);
}

DEV float exp2v(float x) {
#if __has_builtin(__builtin_amdgcn_exp2f)
  return __builtin_amdgcn_exp2f(x);
#else
  float r;
  asm("v_exp_f32 %0, %1" : "=v"(r) : "v"(x));
  return r;
#endif
}

// pack two f32 -> u32 of 2x bf16 (lo = a, hi = b), RNE
DEV uint32_t pkbf(float a, float b) {
  __hip_bfloat162 h = __float22bfloat162_rn(float2{a, b});
  union { __hip_bfloat162 h; uint32_t u; } cv; cv.h = h;
  return cv.u;
}

DEV f32x4 mfma16(bf16x8 a, bf16x8 b, f32x4 c) {
  return __builtin_amdgcn_mfma_f32_16x16x32_bf16(a, b, c, 0, 0, 0);
}

// async global->LDS, 16B per lane. LDS dest = wave-uniform base + lane*16.
DEV void gl_lds16(const void* g, void* l) {
  __builtin_amdgcn_global_load_lds(
      (const __attribute__((address_space(1))) unsigned int*)g,
      (__attribute__((address_space(3))) unsigned int*)l, 16, 0, 0);
}

// ---------------------------------------------------------------- cast f32->bf16 (src==null -> zero fill)
struct CastArgs {
  const float* src[8];
  u16* dst[8];
  int n8[8];
};

__global__ __launch_bounds__(256) void cast_kernel(CastArgs a) {
  const int z = blockIdx.z;
  u16* d = a.dst[z];
  const int n8 = a.n8[z];
  const int stride = gridDim.x * blockDim.x;
  const float* s = a.src[z];
  if (s == nullptr) {
    for (int i = blockIdx.x * blockDim.x + threadIdx.x; i < n8; i += stride)
      *((u16x8*)d + i) = u16x8{0, 0, 0, 0, 0, 0, 0, 0};
    return;
  }
  for (int i = blockIdx.x * blockDim.x + threadIdx.x; i < n8; i += stride) {
    const float4* sp = (const float4*)s + (size_t)i * 2;
    float4 x0 = sp[0], x1 = sp[1];
    u16x8 o;
    o[0] = f2bf(x0.x); o[1] = f2bf(x0.y); o[2] = f2bf(x0.z); o[3] = f2bf(x0.w);
    o[4] = f2bf(x1.x); o[5] = f2bf(x1.y); o[6] = f2bf(x1.z); o[7] = f2bf(x1.w);
    *((u16x8*)d + i) = o;
  }
}

// ---------------------------------------------------------------- GEMM  out = (X @ W^T + bias) * alpha
// mode 0: bf16 row-major out; mode 1: f32 row-major out; mode 2: VT bf16 out [B][H][DH][L]
#define GM 4096
#define GN 1024
#define GK 1024

struct GemmArgs {
  const u16* X[3];
  const u16* W[3];
  const float* bias[3];
  void* out[3];
  float alpha[3];
  int mode[3];
};

__global__ __launch_bounds__(256) void gemm_bt(GemmArgs g) {
  const int z = blockIdx.z;
  const u16* X = g.X[z];
  const u16* W = g.W[z];
  const float* bias = g.bias[z];
  const float alpha = g.alpha[z];
  const int mode = g.mode[z];
  const int m0 = blockIdx.y * 128, n0 = blockIdx.x * 128;

  __shared__ __align__(16) char smem[32 * 1024];
  char* As = smem;            // [128 rows][128B] XOR-swizzled by ((r&7)<<4)
  char* Bs = smem + 16 * 1024;

  const int tid = threadIdx.x;
  const int lane = tid & 63, w = tid >> 6;
  const int l15 = lane & 15, l4 = lane >> 4;
  const int wm = (w >> 1) * 64, wn = (w & 1) * 64;

  f32x4 acc[4][4];
#pragma unroll
  for (int i = 0; i < 4; ++i)
#pragma unroll
    for (int j = 0; j < 4; ++j) acc[i][j] = f32x4{0.f, 0.f, 0.f, 0.f};

  for (int ks = 0; ks < GK; ks += 64) {
    __syncthreads();
    for (int c = w; c < 16; c += 4) {
      int r = c * 8 + (lane >> 3);
      int j = lane & 7;
      int sj = j ^ (r & 7);
      gl_lds16((const char*)(X + (size_t)(m0 + r) * GK + ks) + sj * 16, As + c * 1024);
      gl_lds16((const char*)(W + (size_t)(n0 + r) * GK + ks) + sj * 16, Bs + c * 1024);
    }
    __syncthreads();
#pragma unroll
    for (int ksub = 0; ksub < 2; ++ksub) {
      bf16x8 af[4], bfr[4];
#pragma unroll
      for (int mf = 0; mf < 4; ++mf) {
        int r = wm + mf * 16 + l15;
        int j16 = ksub * 4 + l4;
        af[mf] = *(const bf16x8*)(As + r * 128 + ((j16 ^ (r & 7)) * 16));
      }
#pragma unroll
      for (int nf = 0; nf < 4; ++nf) {
        int r = wn + nf * 16 + l15;
        int j16 = ksub * 4 + l4;
        bfr[nf] = *(const bf16x8*)(Bs + r * 128 + ((j16 ^ (r & 7)) * 16));
      }
#pragma unroll
      for (int mf = 0; mf < 4; ++mf)
#pragma unroll
        for (int nf = 0; nf < 4; ++nf) acc[mf][nf] = mfma16(af[mf], bfr[nf], acc[mf][nf]);
    }
  }

  if (mode == 2) {
    // V projection -> VT [B][H][DH][L]: b=m>>11, l=m&2047, h=n>>6, dh=n&63
    u16* base = (u16*)g.out[z];
#pragma unroll
    for (int nf = 0; nf < 4; ++nf) {
      int n = n0 + wn + nf * 16 + l15;
      float bv = bias[n];
#pragma unroll
      for (int mf = 0; mf < 4; ++mf) {
        int m = m0 + wm + mf * 16 + l4 * 4;
        u16x4 pk;
#pragma unroll
        for (int r = 0; r < 4; ++r) pk[r] = f2bf((acc[mf][nf][r] + bv) * alpha);
        size_t off = (((size_t)(m >> 11) * H_ + (n >> 6)) * DH_ + (n & 63)) * (size_t)L_ + (m & 2047);
        *(u16x4*)(base + off) = pk;
      }
    }
  } else {
#pragma unroll
    for (int nf = 0; nf < 4; ++nf) {
      int n = n0 + wn + nf * 16 + l15;
      float bv = bias[n];
#pragma unroll
      for (int mf = 0; mf < 4; ++mf) {
#pragma unroll
        for (int r = 0; r < 4; ++r) {
          int m = m0 + wm + mf * 16 + l4 * 4 + r;
          float val = (acc[mf][nf][r] + bv) * alpha;
          if (mode == 1)
            ((float*)g.out[z])[(size_t)m * GN + n] = val;
          else
            ((u16*)g.out[z])[(size_t)m * GN + n] = f2bf(val);
        }
      }
    }
  }
}

// ---------------------------------------------------------------- sum-exp kernel
// sums[bh][row] += sum over 512-key chunk of 2^(s - SHIFT2).
__global__ __launch_bounds__(256) void sumexp_kernel(const u16* Qp, const u16* Kp,
                                                     float* sums) {
  const int q0 = blockIdx.x * 64;
  const int kc0 = blockIdx.y * 512;
  const int bh = blockIdx.z;
  const int b = bh >> 4, h = bh & 15;
  const int tid = threadIdx.x, lane = tid & 63, w = tid >> 6;
  const int l15 = lane & 15, l4 = lane >> 4;
  const int lr = lane >> 3, lj = lane & 7;

  __shared__ __align__(16) char smem[16 * 1024];  // K dbuf 8K x2

  const u16* Qbase = Qp + ((size_t)(b * L_ + q0 + w * 16) * D_MODEL_ + h * DH_);
  const u16* Kbase = Kp + ((size_t)(b * L_ + kc0) * D_MODEL_ + h * DH_);

  auto stK = [&](int t) {
    const int c0 = t * 64, bsel = (t & 1) << 13;
    for (int c = w; c < 8; c += 4) {
      int r = c * 8 + lr, sj = lj ^ (r & 7);
      gl_lds16((const char*)(Kbase + (size_t)(c0 + r) * D_MODEL_) + sj * 16,
               smem + bsel + c * 1024);
    }
  };

  bf16x8 qa[2];
#pragma unroll
  for (int ksub = 0; ksub < 2; ++ksub)
    qa[ksub] = *(const bf16x8*)(Qbase + (size_t)l15 * D_MODEL_ + (ksub * 4 + l4) * 8);

  stK(0);
  __syncthreads();

  float ssum = 0.f;
  for (int t = 0; t < 8; ++t) {
    if (t < 7) stK(t + 1);
    const char* Ks = smem + ((t & 1) << 13);
    f32x4 s[4];
#pragma unroll
    for (int nf = 0; nf < 4; ++nf) s[nf] = f32x4{0.f, 0.f, 0.f, 0.f};
#pragma unroll
    for (int ksub = 0; ksub < 2; ++ksub) {
      int j16 = ksub * 4 + l4;
      bf16x8 kb[4];
#pragma unroll
      for (int nf = 0; nf < 4; ++nf) {
        int r = nf * 16 + l15;
        kb[nf] = *(const bf16x8*)(Ks + r * 128 + ((j16 ^ (r & 7)) * 16));
      }
#pragma unroll
      for (int nf = 0; nf < 4; ++nf) s[nf] = mfma16(kb[nf], qa[ksub], s[nf]);
    }
#pragma unroll
    for (int nf = 0; nf < 4; ++nf)
#pragma unroll
      for (int r = 0; r < 4; ++r) ssum += exp2v(s[nf][r] - SHIFT2);
    __syncthreads();
  }

  // merge the 4 l4-groups (different keys, same q-row l15)
  ssum += __shfl_xor(ssum, 16);
  ssum += __shfl_xor(ssum, 32);
  if (lane < 16)
    atomicAdd(&sums[((size_t)bh << 11) + q0 + w * 16 + lane], ssum);
}

// ---------------------------------------------------------------- P writer
// Pure P production: QK^T MFMA -> p = 2^(s - c2) -> wave-private LDS
// transpose -> full-line cached f32 stores. No V, no PV. Structurally
// fill-like: the only memory ops are L2-hit K staging + streaming stores.
// Block: 64 q-rows x 1024 keys (16 tiles). Grid 2048.
__global__ __launch_bounds__(256) void pwrite_kernel(const u16* Qp, const u16* Kp,
                                                     const float* sums, float* attn) {
  const int q0 = blockIdx.x * 64;
  const int h = blockIdx.y;
  const int b = blockIdx.z >> 1;
  const int kc0 = (blockIdx.z & 1) << 10;
  const int tid = threadIdx.x, lane = tid & 63, w = tid >> 6;
  const int l15 = lane & 15, l4 = lane >> 4;
  const int lr = lane >> 3, lj = lane & 7;

  __shared__ __align__(16) char smem[32 * 1024];
  // Pf32: [wave][16 rows][256B] at 0..16K ; K dbuf at 16K + (t&1)*8K
  char* Pw = smem + w * 4096;

  const u16* Qbase = Qp + ((size_t)(b * L_ + q0 + w * 16) * D_MODEL_ + h * DH_);
  const u16* Kbase = Kp + ((size_t)(b * L_ + kc0) * D_MODEL_ + h * DH_);
  float* attnb = attn + ((size_t)(b * H_ + h)) * L_ * L_ + kc0;

  auto stK = [&](int t) {
    const int c0 = t * 64, bsel = (t & 1) << 13;
    for (int c = w; c < 8; c += 4) {
      int r = c * 8 + lr, sj = lj ^ (r & 7);
      gl_lds16((const char*)(Kbase + (size_t)(c0 + r) * D_MODEL_) + sj * 16,
               smem + 16384 + bsel + c * 1024);
    }
  };

  bf16x8 qa[2];
#pragma unroll
  for (int ksub = 0; ksub < 2; ++ksub)
    qa[ksub] = *(const bf16x8*)(Qbase + (size_t)l15 * D_MODEL_ + (ksub * 4 + l4) * 8);

  const float c2 =
      SHIFT2 + __log2f(sums[(((size_t)(b * H_ + h)) << 11) + q0 + w * 16 + l15]);

  stK(0);
  const int swz = l15 & 7;
  float* awave = attnb + (size_t)(q0 + w * 16) * L_;
  __syncthreads();

  for (int t = 0; t < 16; ++t) {
    const int c0 = t * 64;
    if (t < 15) stK(t + 1);
    __builtin_amdgcn_sched_barrier(0);  // staging issues first

    const char* Ks = smem + 16384 + ((t & 1) << 13);
    f32x4 s[4];
#pragma unroll
    for (int nf = 0; nf < 4; ++nf) s[nf] = f32x4{0.f, 0.f, 0.f, 0.f};
    __builtin_amdgcn_s_setprio(1);
#pragma unroll
    for (int ksub = 0; ksub < 2; ++ksub) {
      int j16 = ksub * 4 + l4;
      bf16x8 kb[4];
#pragma unroll
      for (int nf = 0; nf < 4; ++nf) {
        int r = nf * 16 + l15;
        kb[nf] = *(const bf16x8*)(Ks + r * 128 + ((j16 ^ (r & 7)) * 16));
      }
#pragma unroll
      for (int nf = 0; nf < 4; ++nf) s[nf] = mfma16(kb[nf], qa[ksub], s[nf]);
    }
    __builtin_amdgcn_s_setprio(0);

    // p = 2^(s - c2) -> Pf32 LDS (fragment layout, swizzled chunks)
#pragma unroll
    for (int nf = 0; nf < 4; ++nf) {
      f32x4 p4;
#pragma unroll
      for (int r = 0; r < 4; ++r) p4[r] = exp2v(s[nf][r] - c2);
      *(f32x4*)(Pw + l15 * 256 + (((nf * 4 + l4) ^ swz) * 16)) = p4;
    }
    // transposed read -> full-line cached global stores
#pragma unroll
    for (int j = 0; j < 4; ++j) {
      int row = 4 * j + (lane >> 4);
      f32x4 v = *(const f32x4*)(Pw + row * 256 + (((lane & 15) ^ (row & 7)) * 16));
      *(f32x4*)(awave + (size_t)row * L_ + c0 + (lane & 15) * 4) = v;
    }
    if (t < 15) {
      // queue: [4 prev stores][2 staging][4 stores] -> vmcnt(4) retires
      // prev stores + staging, leaves this tile's 4 stores in flight.
      asm volatile("s_waitcnt vmcnt(4)" ::: "memory");
      __builtin_amdgcn_s_barrier();
      __builtin_amdgcn_sched_barrier(0);
    }
  }
}

// ---------------------------------------------------------------- PV kernel
// Recomputes S^T (QK recompute proven free in R9), p = 2^(s-c2), PV MFMA.
// NO P global stores — only 17MB ctx write. K+V LDS dbuf; Pf32 wave-private
// round-trip for the A-fragment rebuild via cvt_pk.
__global__ __launch_bounds__(256) void pv_kernel(const u16* Qp, const u16* Kp,
                                                 const u16* VT, const float* sums,
                                                 u16* ctx) {
  const int q0 = blockIdx.x * 64;
  const int h = blockIdx.y, b = blockIdx.z;
  const int tid = threadIdx.x, lane = tid & 63, w = tid >> 6;
  const int l15 = lane & 15, l4 = lane >> 4;
  const int lr = lane >> 3, lj = lane & 7;

  __shared__ __align__(16) char smem[48 * 1024];
  // Pf32: [wave][16 rows][256B] at 0..16K ; K dbuf at 16K+(t&1)*8K ; V dbuf at 32K+(t&1)*8K
  char* Pw = smem + w * 4096;

  const u16* Qbase = Qp + ((size_t)(b * L_ + q0 + w * 16) * D_MODEL_ + h * DH_);
  const u16* Kbase = Kp + ((size_t)(b * L_) * D_MODEL_ + h * DH_);
  const u16* VTb = VT + ((size_t)((b * H_ + h) * DH_) * L_);

  auto stK = [&](int t) {
    const int c0 = t * 64, bsel = (t & 1) << 13;
    for (int c = w; c < 8; c += 4) {
      int r = c * 8 + lr, sj = lj ^ (r & 7);
      gl_lds16((const char*)(Kbase + (size_t)(c0 + r) * D_MODEL_) + sj * 16,
               smem + 16384 + bsel + c * 1024);
    }
  };
  auto stV = [&](int t) {
    const int c0 = t * 64, bsel = (t & 1) << 13;
    for (int c = w; c < 8; c += 4) {
      int r = c * 8 + lr, sj = lj ^ (r & 7);
      gl_lds16((const char*)(VTb + (size_t)r * L_ + c0) + sj * 16,
               smem + 32768 + bsel + c * 1024);
    }
  };

  bf16x8 qa[2];
#pragma unroll
  for (int ksub = 0; ksub < 2; ++ksub)
    qa[ksub] = *(const bf16x8*)(Qbase + (size_t)l15 * D_MODEL_ + (ksub * 4 + l4) * 8);

  const float c2 =
      SHIFT2 + __log2f(sums[(((size_t)(b * H_ + h)) << 11) + q0 + w * 16 + l15]);

  stK(0);
  stV(0);

  f32x4 cacc[4];
#pragma unroll
  for (int i = 0; i < 4; ++i) cacc[i] = f32x4{0.f, 0.f, 0.f, 0.f};

  const int swz = l15 & 7;
  __syncthreads();

  for (int t = 0; t < 32; ++t) {
    if (t < 31) { stK(t + 1); stV(t + 1); }
    __builtin_amdgcn_sched_barrier(0);

    const char* Ks = smem + 16384 + ((t & 1) << 13);
    const char* Vs = smem + 32768 + ((t & 1) << 13);
    f32x4 s[4];
#pragma unroll
    for (int nf = 0; nf < 4; ++nf) s[nf] = f32x4{0.f, 0.f, 0.f, 0.f};
    __builtin_amdgcn_s_setprio(1);
#pragma unroll
    for (int ksub = 0; ksub < 2; ++ksub) {
      int j16 = ksub * 4 + l4;
      bf16x8 kb[4];
#pragma unroll
      for (int nf = 0; nf < 4; ++nf) {
        int r = nf * 16 + l15;
        kb[nf] = *(const bf16x8*)(Ks + r * 128 + ((j16 ^ (r & 7)) * 16));
      }
#pragma unroll
      for (int nf = 0; nf < 4; ++nf) s[nf] = mfma16(kb[nf], qa[ksub], s[nf]);
    }
    __builtin_amdgcn_s_setprio(0);

    // p -> Pf32 (redistribution only; wave-private, in-order DS)
#pragma unroll
    for (int nf = 0; nf < 4; ++nf) {
      f32x4 p4;
#pragma unroll
      for (int r = 0; r < 4; ++r) p4[r] = exp2v(s[nf][r] - c2);
      *(f32x4*)(Pw + l15 * 256 + (((nf * 4 + l4) ^ swz) * 16)) = p4;
    }
    // PV: rebuild pa (pairs -> bf16), V from LDS
    __builtin_amdgcn_s_setprio(1);
#pragma unroll
    for (int ksub = 0; ksub < 2; ++ksub) {
      int cbase = (ksub * 4 + l4) * 2;
      f32x4 plo = *(const f32x4*)(Pw + l15 * 256 + ((cbase ^ swz) * 16));
      f32x4 phi = *(const f32x4*)(Pw + l15 * 256 + (((cbase + 1) ^ swz) * 16));
      union { u32x4 u; bf16x8 h; } pa;
      pa.u[0] = pkbf(plo[0], plo[1]);
      pa.u[1] = pkbf(plo[2], plo[3]);
      pa.u[2] = pkbf(phi[0], phi[1]);
      pa.u[3] = pkbf(phi[2], phi[3]);
      int j16 = ksub * 4 + l4;
#pragma unroll
      for (int df = 0; df < 4; ++df) {
        int r = df * 16 + l15;
        bf16x8 vb = *(const bf16x8*)(Vs + r * 128 + ((j16 ^ (r & 7)) * 16));
        cacc[df] = mfma16(pa.h, vb, cacc[df]);
      }
    }
    __builtin_amdgcn_s_setprio(0);
    __syncthreads();
  }

  // ctx write (bf16): row = q0 + w*16 + 4*l4 + r, col = h*64 + df*16 + l15
#pragma unroll
  for (int df = 0; df < 4; ++df) {
#pragma unroll
    for (int r = 0; r < 4; ++r) {
      int row = q0 + w * 16 + l4 * 4 + r;
      int col = h * DH_ + df * 16 + l15;
      ctx[(size_t)(b * L_ + row) * D_MODEL_ + col] = f2bf(cacc[df][r]);
    }
  }
}

// ---------------------------------------------------------------- launch
extern "C" void kernel_launch(void* const* d_in, const int* in_sizes, int n_in,
                              void* d_out, int out_size, void* d_ws, size_t ws_size,
                              hipStream_t stream) {
  const float* q = (const float*)d_in[0];
  const float* k = (const float*)d_in[1];
  const float* v = (const float*)d_in[2];
  const float* w_q = (const float*)d_in[3];
  const float* b_q = (const float*)d_in[4];
  const float* w_k = (const float*)d_in[5];
  const float* b_k = (const float*)d_in[6];
  const float* w_v = (const float*)d_in[7];
  const float* b_v = (const float*)d_in[8];
  const float* w_o = (const float*)d_in[9];
  const float* b_o = (const float*)d_in[10];

  float* out = (float*)d_out;
  float* attn = (float*)d_out + (size_t)B_ * L_ * D_MODEL_;

  const size_t MB = 1u << 20;
  char* ws = (char*)d_ws;
  u16* qb = (u16*)(ws + 0 * MB);
  u16* kb = (u16*)(ws + 8 * MB);    // reused as ctx(bf16) after QKV GEMM
  u16* vb = (u16*)(ws + 16 * MB);
  u16* wqb = (u16*)(ws + 24 * MB);
  u16* wkb = (u16*)(ws + 26 * MB);
  u16* wvb = (u16*)(ws + 28 * MB);
  u16* wob = (u16*)(ws + 30 * MB);
  u16* Qp = (u16*)(ws + 32 * MB);
  u16* Kp = (u16*)(ws + 40 * MB);
  u16* VT = (u16*)(ws + 48 * MB);
  float* sums = (float*)(ws + 56 * MB);   // B*H*L f32 = 256KB
  u16* ctx = kb;

  // 1. cast everything to bf16 (+ zero sums)
  CastArgs ca;
  ca.src[0] = q;   ca.dst[0] = qb;  ca.n8[0] = (B_ * L_ * D_MODEL_) / 8;
  ca.src[1] = k;   ca.dst[1] = kb;  ca.n8[1] = (B_ * L_ * D_MODEL_) / 8;
  ca.src[2] = v;   ca.dst[2] = vb;  ca.n8[2] = (B_ * L_ * D_MODEL_) / 8;
  ca.src[3] = w_q; ca.dst[3] = wqb; ca.n8[3] = (D_MODEL_ * D_MODEL_) / 8;
  ca.src[4] = w_k; ca.dst[4] = wkb; ca.n8[4] = (D_MODEL_ * D_MODEL_) / 8;
  ca.src[5] = w_v; ca.dst[5] = wvb; ca.n8[5] = (D_MODEL_ * D_MODEL_) / 8;
  ca.src[6] = w_o; ca.dst[6] = wob; ca.n8[6] = (D_MODEL_ * D_MODEL_) / 8;
  ca.src[7] = nullptr; ca.dst[7] = (u16*)sums; ca.n8[7] = (B_ * H_ * L_ * 4) / 16;
  cast_kernel<<<dim3(1024, 1, 8), 256, 0, stream>>>(ca);

  // 2. QKV projections. Q's alpha folds 1/8 (score scale) * log2(e) (base-2 exp domain).
  GemmArgs ga;
  ga.X[0] = qb;  ga.W[0] = wqb; ga.bias[0] = b_q; ga.out[0] = Qp; ga.alpha[0] = 0.125f * 1.44269504f; ga.mode[0] = 0;
  ga.X[1] = kb;  ga.W[1] = wkb; ga.bias[1] = b_k; ga.out[1] = Kp; ga.alpha[1] = 1.f;    ga.mode[1] = 0;
  ga.X[2] = vb;  ga.W[2] = wvb; ga.bias[2] = b_v; ga.out[2] = VT; ga.alpha[2] = 1.f;    ga.mode[2] = 2;
  gemm_bt<<<dim3(8, 32, 3), 256, 0, stream>>>(ga);

  // 3a. row sums of 2^(s-SHIFT2)
  sumexp_kernel<<<dim3(32, 4, 32), 256, 0, stream>>>(Qp, Kp, sums);

  // 3b. P writer: pure streaming-store kernel (the diagnostic)
  pwrite_kernel<<<dim3(32, 16, 4), 256, 0, stream>>>(Qp, Kp, sums, attn);

  // 3c. PV: ctx only, no P stores
  pv_kernel<<<dim3(32, 16, 2), 256, 0, stream>>>(Qp, Kp, VT, sums, ctx);

  // 4. output projection (f32 out + bias)
  GemmArgs go;
  go.X[0] = ctx; go.W[0] = wob; go.bias[0] = b_o; go.out[0] = out; go.alpha[0] = 1.f; go.mode[0] = 1;
  go.X[1] = ctx; go.W[1] = wob; go.bias[1] = b_o; go.out[1] = out; go.alpha[1] = 1.f; go.mode[1] = 1;
  go.X[2] = ctx; go.W[2] = wob; go.bias[2] = b_o; go.out[2] = out; go.alpha[2] = 1.f; go.mode[2] = 1;
  gemm_bt<<<dim3(8, 32, 1), 256, 0, stream>>>(go);
}

// Round 14
// 341.383 us; speedup vs baseline: 1.0065x; 1.0065x over previous
//
#include <hip/hip_runtime.h>
#include <hip/hip_bf16.h>
#include <stdint.h>

#define DEV static __device__ __forceinline__

typedef float f32x4 __attribute__((ext_vector_type(4)));
typedef __bf16 bf16x8 __attribute__((ext_vector_type(8)));
typedef unsigned short u16x8 __attribute__((ext_vector_type(8)));
typedef unsigned short u16x4 __attribute__((ext_vector_type(4)));
typedef uint32_t u32x4 __attribute__((ext_vector_type(4)));
typedef unsigned short u16;

#define B_ 2
#define L_ 2048
#define D_MODEL_ 1024
#define H_ 16
#define DH_ 64

// shift in base-2 score domain: 8 (base-e) * log2(e)
#define SHIFT2 11.5415603f

DEV u16 f2bf(float f) {
  union { float f; uint32_t u; } v; v.f = f;
  uint32_t r = v.u + 0x7FFFu + ((v.u >> 16) & 1u);  // RNE
  return (u16)(r >> 16);
}

DEV float exp2v(float x) {
#if __has_builtin(__builtin_amdgcn_exp2f)
  return __builtin_amdgcn_exp2f(x);
#else
  float r;
  asm("v_exp_f32 %0, %1" : "=v"(r) : "v"(x));
  return r;
#endif
}

// pack two f32 -> u32 of 2x bf16 (lo = a, hi = b), RNE
DEV uint32_t pkbf(float a, float b) {
  __hip_bfloat162 h = __float22bfloat162_rn(float2{a, b});
  union { __hip_bfloat162 h; uint32_t u; } cv; cv.h = h;
  return cv.u;
}

DEV f32x4 mfma16(bf16x8 a, bf16x8 b, f32x4 c) {
  return __builtin_amdgcn_mfma_f32_16x16x32_bf16(a, b, c, 0, 0, 0);
}

// async global->LDS, 16B per lane. LDS dest = wave-uniform base + lane*16.
DEV void gl_lds16(const void* g, void* l) {
  __builtin_amdgcn_global_load_lds(
      (const __attribute__((address_space(1))) unsigned int*)g,
      (__attribute__((address_space(3))) unsigned int*)l, 16, 0, 0);
}

// ---------------------------------------------------------------- cast f32->bf16 (src==null -> zero fill)
struct CastArgs {
  const float* src[8];
  u16* dst[8];
  int n8[8];
};

__global__ __launch_bounds__(256) void cast_kernel(CastArgs a) {
  const int z = blockIdx.z;
  u16* d = a.dst[z];
  const int n8 = a.n8[z];
  const int stride = gridDim.x * blockDim.x;
  const float* s = a.src[z];
  if (s == nullptr) {
    for (int i = blockIdx.x * blockDim.x + threadIdx.x; i < n8; i += stride)
      *((u16x8*)d + i) = u16x8{0, 0, 0, 0, 0, 0, 0, 0};
    return;
  }
  for (int i = blockIdx.x * blockDim.x + threadIdx.x; i < n8; i += stride) {
    const float4* sp = (const float4*)s + (size_t)i * 2;
    float4 x0 = sp[0], x1 = sp[1];
    u16x8 o;
    o[0] = f2bf(x0.x); o[1] = f2bf(x0.y); o[2] = f2bf(x0.z); o[3] = f2bf(x0.w);
    o[4] = f2bf(x1.x); o[5] = f2bf(x1.y); o[6] = f2bf(x1.z); o[7] = f2bf(x1.w);
    *((u16x8*)d + i) = o;
  }
}

// ---------------------------------------------------------------- GEMM  out = (X @ W^T + bias) * alpha
// mode 0: bf16 row-major out; mode 1: f32 row-major out; mode 2: VT bf16 out [B][H][DH][L]
#define GM 4096
#define GN 1024
#define GK 1024

struct GemmArgs {
  const u16* X[3];
  const u16* W[3];
  const float* bias[3];
  void* out[3];
  float alpha[3];
  int mode[3];
};

__global__ __launch_bounds__(256) void gemm_bt(GemmArgs g) {
  const int z = blockIdx.z;
  const u16* X = g.X[z];
  const u16* W = g.W[z];
  const float* bias = g.bias[z];
  const float alpha = g.alpha[z];
  const int mode = g.mode[z];
  const int m0 = blockIdx.y * 128, n0 = blockIdx.x * 128;

  __shared__ __align__(16) char smem[32 * 1024];
  char* As = smem;            // [128 rows][128B] XOR-swizzled by ((r&7)<<4)
  char* Bs = smem + 16 * 1024;

  const int tid = threadIdx.x;
  const int lane = tid & 63, w = tid >> 6;
  const int l15 = lane & 15, l4 = lane >> 4;
  const int wm = (w >> 1) * 64, wn = (w & 1) * 64;

  f32x4 acc[4][4];
#pragma unroll
  for (int i = 0; i < 4; ++i)
#pragma unroll
    for (int j = 0; j < 4; ++j) acc[i][j] = f32x4{0.f, 0.f, 0.f, 0.f};

  for (int ks = 0; ks < GK; ks += 64) {
    __syncthreads();
    for (int c = w; c < 16; c += 4) {
      int r = c * 8 + (lane >> 3);
      int j = lane & 7;
      int sj = j ^ (r & 7);
      gl_lds16((const char*)(X + (size_t)(m0 + r) * GK + ks) + sj * 16, As + c * 1024);
      gl_lds16((const char*)(W + (size_t)(n0 + r) * GK + ks) + sj * 16, Bs + c * 1024);
    }
    __syncthreads();
#pragma unroll
    for (int ksub = 0; ksub < 2; ++ksub) {
      bf16x8 af[4], bfr[4];
#pragma unroll
      for (int mf = 0; mf < 4; ++mf) {
        int r = wm + mf * 16 + l15;
        int j16 = ksub * 4 + l4;
        af[mf] = *(const bf16x8*)(As + r * 128 + ((j16 ^ (r & 7)) * 16));
      }
#pragma unroll
      for (int nf = 0; nf < 4; ++nf) {
        int r = wn + nf * 16 + l15;
        int j16 = ksub * 4 + l4;
        bfr[nf] = *(const bf16x8*)(Bs + r * 128 + ((j16 ^ (r & 7)) * 16));
      }
#pragma unroll
      for (int mf = 0; mf < 4; ++mf)
#pragma unroll
        for (int nf = 0; nf < 4; ++nf) acc[mf][nf] = mfma16(af[mf], bfr[nf], acc[mf][nf]);
    }
  }

  if (mode == 2) {
    // V projection -> VT [B][H][DH][L]: b=m>>11, l=m&2047, h=n>>6, dh=n&63
    u16* base = (u16*)g.out[z];
#pragma unroll
    for (int nf = 0; nf < 4; ++nf) {
      int n = n0 + wn + nf * 16 + l15;
      float bv = bias[n];
#pragma unroll
      for (int mf = 0; mf < 4; ++mf) {
        int m = m0 + wm + mf * 16 + l4 * 4;
        u16x4 pk;
#pragma unroll
        for (int r = 0; r < 4; ++r) pk[r] = f2bf((acc[mf][nf][r] + bv) * alpha);
        size_t off = (((size_t)(m >> 11) * H_ + (n >> 6)) * DH_ + (n & 63)) * (size_t)L_ + (m & 2047);
        *(u16x4*)(base + off) = pk;
      }
    }
  } else {
#pragma unroll
    for (int nf = 0; nf < 4; ++nf) {
      int n = n0 + wn + nf * 16 + l15;
      float bv = bias[n];
#pragma unroll
      for (int mf = 0; mf < 4; ++mf) {
#pragma unroll
        for (int r = 0; r < 4; ++r) {
          int m = m0 + wm + mf * 16 + l4 * 4 + r;
          float val = (acc[mf][nf][r] + bv) * alpha;
          if (mode == 1)
            ((float*)g.out[z])[(size_t)m * GN + n] = val;
          else
            ((u16*)g.out[z])[(size_t)m * GN + n] = f2bf(val);
        }
      }
    }
  }
}

// ---------------------------------------------------------------- sum-exp kernel
// sums[bh][row] += sum over 512-key chunk of 2^(s - SHIFT2).
__global__ __launch_bounds__(256) void sumexp_kernel(const u16* Qp, const u16* Kp,
                                                     float* sums) {
  const int q0 = blockIdx.x * 64;
  const int kc0 = blockIdx.y * 512;
  const int bh = blockIdx.z;
  const int b = bh >> 4, h = bh & 15;
  const int tid = threadIdx.x, lane = tid & 63, w = tid >> 6;
  const int l15 = lane & 15, l4 = lane >> 4;
  const int lr = lane >> 3, lj = lane & 7;

  __shared__ __align__(16) char smem[16 * 1024];  // K dbuf 8K x2

  const u16* Qbase = Qp + ((size_t)(b * L_ + q0 + w * 16) * D_MODEL_ + h * DH_);
  const u16* Kbase = Kp + ((size_t)(b * L_ + kc0) * D_MODEL_ + h * DH_);

  auto stK = [&](int t) {
    const int c0 = t * 64, bsel = (t & 1) << 13;
    for (int c = w; c < 8; c += 4) {
      int r = c * 8 + lr, sj = lj ^ (r & 7);
      gl_lds16((const char*)(Kbase + (size_t)(c0 + r) * D_MODEL_) + sj * 16,
               smem + bsel + c * 1024);
    }
  };

  bf16x8 qa[2];
#pragma unroll
  for (int ksub = 0; ksub < 2; ++ksub)
    qa[ksub] = *(const bf16x8*)(Qbase + (size_t)l15 * D_MODEL_ + (ksub * 4 + l4) * 8);

  stK(0);
  __syncthreads();

  float ssum = 0.f;
  for (int t = 0; t < 8; ++t) {
    if (t < 7) stK(t + 1);
    const char* Ks = smem + ((t & 1) << 13);
    f32x4 s[4];
#pragma unroll
    for (int nf = 0; nf < 4; ++nf) s[nf] = f32x4{0.f, 0.f, 0.f, 0.f};
#pragma unroll
    for (int ksub = 0; ksub < 2; ++ksub) {
      int j16 = ksub * 4 + l4;
      bf16x8 kb[4];
#pragma unroll
      for (int nf = 0; nf < 4; ++nf) {
        int r = nf * 16 + l15;
        kb[nf] = *(const bf16x8*)(Ks + r * 128 + ((j16 ^ (r & 7)) * 16));
      }
#pragma unroll
      for (int nf = 0; nf < 4; ++nf) s[nf] = mfma16(kb[nf], qa[ksub], s[nf]);
    }
#pragma unroll
    for (int nf = 0; nf < 4; ++nf)
#pragma unroll
      for (int r = 0; r < 4; ++r) ssum += exp2v(s[nf][r] - SHIFT2);
    __syncthreads();
  }

  // merge the 4 l4-groups (different keys, same q-row l15)
  ssum += __shfl_xor(ssum, 16);
  ssum += __shfl_xor(ssum, 32);
  if (lane < 16)
    atomicAdd(&sums[((size_t)bh << 11) + q0 + w * 16 + lane], ssum);
}

// ---------------------------------------------------------------- fused attention, single-wave blocks
// One 64-lane wave per block owns 16 q-rows x ALL 2048 keys. ZERO barriers:
// K staged into WAVE-PRIVATE LDS dbuf via coalesced global_load_lds (in-order
// vmcnt retirement gives dbuf correctness within the wave); V direct
// global->reg (proven neutral R8-R12); Q direct; row sums precomputed.
// p = 2^(s-c2) -> wave-private Pf32 transpose -> full-line cached stores.
// 8 independent waves/CU (20KB LDS) in freely differing phases: one wave's
// store burst overlaps another's MFMA/exp — fill-kernel-style TLP.
__global__ __launch_bounds__(64) void attn_kernel(const u16* Qp, const u16* Kp,
                                                  const u16* VT, const float* sums,
                                                  float* attn, u16* ctx) {
  const int q0 = blockIdx.x * 16;
  const int h = blockIdx.y, b = blockIdx.z;
  const int lane = threadIdx.x & 63;
  const int l15 = lane & 15, l4 = lane >> 4;
  const int lr = lane >> 3, lj = lane & 7;

  __shared__ __align__(16) char smem[20 * 1024];
  // K dbuf at (t&1)*8K ; Pf32 [16 rows][256B] at 16K
  char* Pw = smem + 16384;

  const u16* Qbase = Qp + ((size_t)(b * L_ + q0) * D_MODEL_ + h * DH_);
  const u16* Kbase = Kp + ((size_t)(b * L_) * D_MODEL_ + h * DH_);
  const u16* Vb = VT + ((size_t)((b * H_ + h) * DH_) * L_);
  float* attnb = attn + ((size_t)(b * H_ + h)) * L_ * L_;

  auto stK = [&](int t) {
    const int c0 = t * 64, bsel = (t & 1) << 13;
#pragma unroll
    for (int c = 0; c < 8; ++c) {
      int r = c * 8 + lr, sj = lj ^ (r & 7);
      gl_lds16((const char*)(Kbase + (size_t)(c0 + r) * D_MODEL_) + sj * 16,
               smem + bsel + c * 1024);
    }
  };

  // Q fragments direct (rows q0+l15, col-chunk (ksub*4+l4)*8)
  bf16x8 qa[2];
#pragma unroll
  for (int ksub = 0; ksub < 2; ++ksub)
    qa[ksub] = *(const bf16x8*)(Qbase + (size_t)l15 * D_MODEL_ + (ksub * 4 + l4) * 8);

  const float c2 =
      SHIFT2 + __log2f(sums[(((size_t)(b * H_ + h)) << 11) + q0 + l15]);

  stK(0);

  f32x4 cacc[4];
#pragma unroll
  for (int i = 0; i < 4; ++i) cacc[i] = f32x4{0.f, 0.f, 0.f, 0.f};

  const int swz = l15 & 7;

  for (int t = 0; t < 32; ++t) {
    const int c0 = t * 64;
    const char* Ks = smem + ((t & 1) << 13);

    // K fragments from wave-private LDS (compiler inserts the vmcnt wait for
    // the staging of this buffer; in-order retirement makes it cheap)
    f32x4 s[4];
#pragma unroll
    for (int nf = 0; nf < 4; ++nf) s[nf] = f32x4{0.f, 0.f, 0.f, 0.f};
    __builtin_amdgcn_s_setprio(1);
#pragma unroll
    for (int ksub = 0; ksub < 2; ++ksub) {
      int j16 = ksub * 4 + l4;
      bf16x8 kb[4];
#pragma unroll
      for (int nf = 0; nf < 4; ++nf) {
        int r = nf * 16 + l15;
        kb[nf] = *(const bf16x8*)(Ks + r * 128 + ((j16 ^ (r & 7)) * 16));
      }
#pragma unroll
      for (int nf = 0; nf < 4; ++nf) s[nf] = mfma16(kb[nf], qa[ksub], s[nf]);
    }
    __builtin_amdgcn_s_setprio(0);

    // stage NEXT K tile after this tile's LDS reads are done issuing
    if (t < 31) stK(t + 1);
    // V fragments for THIS tile (direct; consumed at PV below)
    bf16x8 va[2][4];
#pragma unroll
    for (int ksub = 0; ksub < 2; ++ksub)
#pragma unroll
      for (int df = 0; df < 4; ++df)
        va[ksub][df] = *(const bf16x8*)(Vb + (size_t)(df * 16 + l15) * L_ + c0 +
                                        (ksub * 4 + l4) * 8);

    // p = 2^(s - c2) -> Pf32 (wave-private, in-order DS)
#pragma unroll
    for (int nf = 0; nf < 4; ++nf) {
      f32x4 p4;
#pragma unroll
      for (int r = 0; r < 4; ++r) p4[r] = exp2v(s[nf][r] - c2);
      *(f32x4*)(Pw + l15 * 256 + (((nf * 4 + l4) ^ swz) * 16)) = p4;
    }
    // transposed read -> full-line cached global stores
    float* awave = attnb + (size_t)q0 * L_ + c0;
#pragma unroll
    for (int j = 0; j < 4; ++j) {
      int row = 4 * j + (lane >> 4);
      f32x4 v = *(const f32x4*)(Pw + row * 256 + (((lane & 15) ^ (row & 7)) * 16));
      *(f32x4*)(awave + (size_t)row * L_ + (lane & 15) * 4) = v;
    }
    // PV: rebuild pa from Pf32 (pairs -> bf16), V from regs
    __builtin_amdgcn_s_setprio(1);
#pragma unroll
    for (int ksub = 0; ksub < 2; ++ksub) {
      int cbase = (ksub * 4 + l4) * 2;
      f32x4 plo = *(const f32x4*)(Pw + l15 * 256 + ((cbase ^ swz) * 16));
      f32x4 phi = *(const f32x4*)(Pw + l15 * 256 + (((cbase + 1) ^ swz) * 16));
      union { u32x4 u; bf16x8 h; } pa;
      pa.u[0] = pkbf(plo[0], plo[1]);
      pa.u[1] = pkbf(plo[2], plo[3]);
      pa.u[2] = pkbf(phi[0], phi[1]);
      pa.u[3] = pkbf(phi[2], phi[3]);
#pragma unroll
      for (int df = 0; df < 4; ++df)
        cacc[df] = mfma16(pa.h, va[ksub][df], cacc[df]);
    }
    __builtin_amdgcn_s_setprio(0);
    // no barrier — next iteration's K reads depend on stK(t+1) via vmcnt only
  }

  // ctx write (bf16): row = q0 + 4*l4 + r, col = h*64 + df*16 + l15
#pragma unroll
  for (int df = 0; df < 4; ++df) {
#pragma unroll
    for (int r = 0; r < 4; ++r) {
      int row = q0 + l4 * 4 + r;
      int col = h * DH_ + df * 16 + l15;
      ctx[(size_t)(b * L_ + row) * D_MODEL_ + col] = f2bf(cacc[df][r]);
    }
  }
}

// ---------------------------------------------------------------- launch
extern "C" void kernel_launch(void* const* d_in, const int* in_sizes, int n_in,
                              void* d_out, int out_size, void* d_ws, size_t ws_size,
                              hipStream_t stream) {
  const float* q = (const float*)d_in[0];
  const float* k = (const float*)d_in[1];
  const float* v = (const float*)d_in[2];
  const float* w_q = (const float*)d_in[3];
  const float* b_q = (const float*)d_in[4];
  const float* w_k = (const float*)d_in[5];
  const float* b_k = (const float*)d_in[6];
  const float* w_v = (const float*)d_in[7];
  const float* b_v = (const float*)d_in[8];
  const float* w_o = (const float*)d_in[9];
  const float* b_o = (const float*)d_in[10];

  float* out = (float*)d_out;
  float* attn = (float*)d_out + (size_t)B_ * L_ * D_MODEL_;

  const size_t MB = 1u << 20;
  char* ws = (char*)d_ws;
  u16* qb = (u16*)(ws + 0 * MB);
  u16* kb = (u16*)(ws + 8 * MB);    // reused as ctx(bf16) after QKV GEMM
  u16* vb = (u16*)(ws + 16 * MB);
  u16* wqb = (u16*)(ws + 24 * MB);
  u16* wkb = (u16*)(ws + 26 * MB);
  u16* wvb = (u16*)(ws + 28 * MB);
  u16* wob = (u16*)(ws + 30 * MB);
  u16* Qp = (u16*)(ws + 32 * MB);
  u16* Kp = (u16*)(ws + 40 * MB);
  u16* VT = (u16*)(ws + 48 * MB);
  float* sums = (float*)(ws + 56 * MB);   // B*H*L f32 = 256KB
  u16* ctx = kb;

  // 1. cast everything to bf16 (+ zero sums)
  CastArgs ca;
  ca.src[0] = q;   ca.dst[0] = qb;  ca.n8[0] = (B_ * L_ * D_MODEL_) / 8;
  ca.src[1] = k;   ca.dst[1] = kb;  ca.n8[1] = (B_ * L_ * D_MODEL_) / 8;
  ca.src[2] = v;   ca.dst[2] = vb;  ca.n8[2] = (B_ * L_ * D_MODEL_) / 8;
  ca.src[3] = w_q; ca.dst[3] = wqb; ca.n8[3] = (D_MODEL_ * D_MODEL_) / 8;
  ca.src[4] = w_k; ca.dst[4] = wkb; ca.n8[4] = (D_MODEL_ * D_MODEL_) / 8;
  ca.src[5] = w_v; ca.dst[5] = wvb; ca.n8[5] = (D_MODEL_ * D_MODEL_) / 8;
  ca.src[6] = w_o; ca.dst[6] = wob; ca.n8[6] = (D_MODEL_ * D_MODEL_) / 8;
  ca.src[7] = nullptr; ca.dst[7] = (u16*)sums; ca.n8[7] = (B_ * H_ * L_ * 4) / 16;
  cast_kernel<<<dim3(1024, 1, 8), 256, 0, stream>>>(ca);

  // 2. QKV projections. Q's alpha folds 1/8 (score scale) * log2(e) (base-2 exp domain).
  GemmArgs ga;
  ga.X[0] = qb;  ga.W[0] = wqb; ga.bias[0] = b_q; ga.out[0] = Qp; ga.alpha[0] = 0.125f * 1.44269504f; ga.mode[0] = 0;
  ga.X[1] = kb;  ga.W[1] = wkb; ga.bias[1] = b_k; ga.out[1] = Kp; ga.alpha[1] = 1.f;    ga.mode[1] = 0;
  ga.X[2] = vb;  ga.W[2] = wvb; ga.bias[2] = b_v; ga.out[2] = VT; ga.alpha[2] = 1.f;    ga.mode[2] = 2;
  gemm_bt<<<dim3(8, 32, 3), 256, 0, stream>>>(ga);

  // 3a. row sums of 2^(s-SHIFT2)
  sumexp_kernel<<<dim3(32, 4, 32), 256, 0, stream>>>(Qp, Kp, sums);

  // 3b. fused attention: single-wave blocks, zero barriers
  attn_kernel<<<dim3(128, 16, 2), 64, 0, stream>>>(Qp, Kp, VT, sums, attn, ctx);

  // 4. output projection (f32 out + bias)
  GemmArgs go;
  go.X[0] = ctx; go.W[0] = wob; go.bias[0] = b_o; go.out[0] = out; go.alpha[0] = 1.f; go.mode[0] = 1;
  go.X[1] = ctx; go.W[1] = wob; go.bias[1] = b_o; go.out[1] = out; go.alpha[1] = 1.f; go.mode[1] = 1;
  go.X[2] = ctx; go.W[2] = wob; go.bias[2] = b_o; go.out[2] = out; go.alpha[2] = 1.f; go.mode[2] = 1;
  gemm_bt<<<dim3(8, 32, 1), 256, 0, stream>>>(go);
}

// Round 15
// 304.045 us; speedup vs baseline: 1.1301x; 1.1228x over previous
//
#include <hip/hip_runtime.h>
#include <hip/hip_bf16.h>
#include <stdint.h>

#define DEV static __device__ __forceinline__

typedef float f32x4 __attribute__((ext_vector_type(4)));
typedef __bf16 bf16x8 __attribute__((ext_vector_type(8)));
typedef unsigned short u16x8 __attribute__((ext_vector_type(8)));
typedef unsigned short u16x4 __attribute__((ext_vector_type(4)));
typedef uint32_t u32x4 __attribute__((ext_vector_type(4)));
typedef unsigned short u16;

#define B_ 2
#define L_ 2048
#define D_MODEL_ 1024
#define H_ 16
#define DH_ 64

// shift in base-2 score domain: 8 (base-e) * log2(e)
#define SHIFT2 11.5415603f

DEV u16 f2bf(float f) {
  union { float f; uint32_t u; } v; v.f = f;
  uint32_t r = v.u + 0x7FFFu + ((v.u >> 16) & 1u);  // RNE
  return (u16)(r >> 16);
}

DEV float exp2v(float x) {
#if __has_builtin(__builtin_amdgcn_exp2f)
  return __builtin_amdgcn_exp2f(x);
#else
  float r;
  asm("v_exp_f32 %0, %1" : "=v"(r) : "v"(x));
  return r;
#endif
}

// pack two f32 -> u32 of 2x bf16 (lo = a, hi = b), RNE
DEV uint32_t pkbf(float a, float b) {
  __hip_bfloat162 h = __float22bfloat162_rn(float2{a, b});
  union { __hip_bfloat162 h; uint32_t u; } cv; cv.h = h;
  return cv.u;
}

DEV f32x4 mfma16(bf16x8 a, bf16x8 b, f32x4 c) {
  return __builtin_amdgcn_mfma_f32_16x16x32_bf16(a, b, c, 0, 0, 0);
}

// async global->LDS, 16B per lane. LDS dest = wave-uniform base + lane*16.
DEV void gl_lds16(const void* g, void* l) {
  __builtin_amdgcn_global_load_lds(
      (const __attribute__((address_space(1))) unsigned int*)g,
      (__attribute__((address_space(3))) unsigned int*)l, 16, 0, 0);
}

// ---------------------------------------------------------------- cast f32->bf16 (src==null -> zero fill)
struct CastArgs {
  const float* src[8];
  u16* dst[8];
  int n8[8];
};

__global__ __launch_bounds__(256) void cast_kernel(CastArgs a) {
  const int z = blockIdx.z;
  u16* d = a.dst[z];
  const int n8 = a.n8[z];
  const int stride = gridDim.x * blockDim.x;
  const float* s = a.src[z];
  if (s == nullptr) {
    for (int i = blockIdx.x * blockDim.x + threadIdx.x; i < n8; i += stride)
      *((u16x8*)d + i) = u16x8{0, 0, 0, 0, 0, 0, 0, 0};
    return;
  }
  for (int i = blockIdx.x * blockDim.x + threadIdx.x; i < n8; i += stride) {
    const float4* sp = (const float4*)s + (size_t)i * 2;
    float4 x0 = sp[0], x1 = sp[1];
    u16x8 o;
    o[0] = f2bf(x0.x); o[1] = f2bf(x0.y); o[2] = f2bf(x0.z); o[3] = f2bf(x0.w);
    o[4] = f2bf(x1.x); o[5] = f2bf(x1.y); o[6] = f2bf(x1.z); o[7] = f2bf(x1.w);
    *((u16x8*)d + i) = o;
  }
}

// ---------------------------------------------------------------- GEMM  out = (X @ W^T + bias) * alpha
// mode 0: bf16 row-major out; mode 1: f32 row-major out; mode 2: VT bf16 out [B][H][DH][L]
#define GM 4096
#define GN 1024
#define GK 1024

struct GemmArgs {
  const u16* X[3];
  const u16* W[3];
  const float* bias[3];
  void* out[3];
  float alpha[3];
  int mode[3];
};

__global__ __launch_bounds__(256) void gemm_bt(GemmArgs g) {
  const int z = blockIdx.z;
  const u16* X = g.X[z];
  const u16* W = g.W[z];
  const float* bias = g.bias[z];
  const float alpha = g.alpha[z];
  const int mode = g.mode[z];
  const int m0 = blockIdx.y * 128, n0 = blockIdx.x * 128;

  __shared__ __align__(16) char smem[32 * 1024];
  char* As = smem;            // [128 rows][128B] XOR-swizzled by ((r&7)<<4)
  char* Bs = smem + 16 * 1024;

  const int tid = threadIdx.x;
  const int lane = tid & 63, w = tid >> 6;
  const int l15 = lane & 15, l4 = lane >> 4;
  const int wm = (w >> 1) * 64, wn = (w & 1) * 64;

  f32x4 acc[4][4];
#pragma unroll
  for (int i = 0; i < 4; ++i)
#pragma unroll
    for (int j = 0; j < 4; ++j) acc[i][j] = f32x4{0.f, 0.f, 0.f, 0.f};

  for (int ks = 0; ks < GK; ks += 64) {
    __syncthreads();
    for (int c = w; c < 16; c += 4) {
      int r = c * 8 + (lane >> 3);
      int j = lane & 7;
      int sj = j ^ (r & 7);
      gl_lds16((const char*)(X + (size_t)(m0 + r) * GK + ks) + sj * 16, As + c * 1024);
      gl_lds16((const char*)(W + (size_t)(n0 + r) * GK + ks) + sj * 16, Bs + c * 1024);
    }
    __syncthreads();
#pragma unroll
    for (int ksub = 0; ksub < 2; ++ksub) {
      bf16x8 af[4], bfr[4];
#pragma unroll
      for (int mf = 0; mf < 4; ++mf) {
        int r = wm + mf * 16 + l15;
        int j16 = ksub * 4 + l4;
        af[mf] = *(const bf16x8*)(As + r * 128 + ((j16 ^ (r & 7)) * 16));
      }
#pragma unroll
      for (int nf = 0; nf < 4; ++nf) {
        int r = wn + nf * 16 + l15;
        int j16 = ksub * 4 + l4;
        bfr[nf] = *(const bf16x8*)(Bs + r * 128 + ((j16 ^ (r & 7)) * 16));
      }
#pragma unroll
      for (int mf = 0; mf < 4; ++mf)
#pragma unroll
        for (int nf = 0; nf < 4; ++nf) acc[mf][nf] = mfma16(af[mf], bfr[nf], acc[mf][nf]);
    }
  }

  if (mode == 2) {
    // V projection -> VT [B][H][DH][L]: b=m>>11, l=m&2047, h=n>>6, dh=n&63
    u16* base = (u16*)g.out[z];
#pragma unroll
    for (int nf = 0; nf < 4; ++nf) {
      int n = n0 + wn + nf * 16 + l15;
      float bv = bias[n];
#pragma unroll
      for (int mf = 0; mf < 4; ++mf) {
        int m = m0 + wm + mf * 16 + l4 * 4;
        u16x4 pk;
#pragma unroll
        for (int r = 0; r < 4; ++r) pk[r] = f2bf((acc[mf][nf][r] + bv) * alpha);
        size_t off = (((size_t)(m >> 11) * H_ + (n >> 6)) * DH_ + (n & 63)) * (size_t)L_ + (m & 2047);
        *(u16x4*)(base + off) = pk;
      }
    }
  } else {
#pragma unroll
    for (int nf = 0; nf < 4; ++nf) {
      int n = n0 + wn + nf * 16 + l15;
      float bv = bias[n];
#pragma unroll
      for (int mf = 0; mf < 4; ++mf) {
#pragma unroll
        for (int r = 0; r < 4; ++r) {
          int m = m0 + wm + mf * 16 + l4 * 4 + r;
          float val = (acc[mf][nf][r] + bv) * alpha;
          if (mode == 1)
            ((float*)g.out[z])[(size_t)m * GN + n] = val;
          else
            ((u16*)g.out[z])[(size_t)m * GN + n] = f2bf(val);
        }
      }
    }
  }
}

// ---------------------------------------------------------------- sum-exp, 128x128-tile GEMM structure
// Block: 128 q-rows x 128 keys for one (b,h). Stage Q-tile (16KB) + K-tile
// (16KB) once, 32 MFMA/wave over K=64, exp-reduce fragments over keys:
// 4 shfl_xor rounds across the l15 group, then one atomicAdd per (row,ktile).
__global__ __launch_bounds__(256) void sumexp_kernel(const u16* Qp, const u16* Kp,
                                                     float* sums) {
  const int m0 = blockIdx.x * 128;   // q rows
  const int n0 = blockIdx.y * 128;   // keys
  const int bh = blockIdx.z;
  const int b = bh >> 4, h = bh & 15;
  const int tid = threadIdx.x, lane = tid & 63, w = tid >> 6;
  const int l15 = lane & 15, l4 = lane >> 4;
  const int wm = (w >> 1) * 64, wn = (w & 1) * 64;

  __shared__ __align__(16) char smem[32 * 1024];
  char* As = smem;             // Q tile [128 rows][128B], swizzled
  char* Bs = smem + 16 * 1024; // K tile

  const u16* Qb = Qp + ((size_t)(b * L_ + m0) * D_MODEL_ + h * DH_);
  const u16* Kb = Kp + ((size_t)(b * L_ + n0) * D_MODEL_ + h * DH_);

  for (int c = w; c < 16; c += 4) {
    int r = c * 8 + (lane >> 3);
    int j = lane & 7;
    int sj = j ^ (r & 7);
    gl_lds16((const char*)(Qb + (size_t)r * D_MODEL_) + sj * 16, As + c * 1024);
    gl_lds16((const char*)(Kb + (size_t)r * D_MODEL_) + sj * 16, Bs + c * 1024);
  }
  __syncthreads();

  f32x4 acc[4][4];
#pragma unroll
  for (int i = 0; i < 4; ++i)
#pragma unroll
    for (int j = 0; j < 4; ++j) acc[i][j] = f32x4{0.f, 0.f, 0.f, 0.f};

#pragma unroll
  for (int ksub = 0; ksub < 2; ++ksub) {
    bf16x8 af[4], bfr[4];
#pragma unroll
    for (int mf = 0; mf < 4; ++mf) {
      int r = wm + mf * 16 + l15;
      int j16 = ksub * 4 + l4;
      af[mf] = *(const bf16x8*)(As + r * 128 + ((j16 ^ (r & 7)) * 16));
    }
#pragma unroll
    for (int nf = 0; nf < 4; ++nf) {
      int r = wn + nf * 16 + l15;
      int j16 = ksub * 4 + l4;
      bfr[nf] = *(const bf16x8*)(Bs + r * 128 + ((j16 ^ (r & 7)) * 16));
    }
#pragma unroll
    for (int mf = 0; mf < 4; ++mf)
#pragma unroll
      for (int nf = 0; nf < 4; ++nf) acc[mf][nf] = mfma16(af[mf], bfr[nf], acc[mf][nf]);
  }

  // exp-reduce: per (mf, r) sum over this lane's 4 keys, then over the 16-lane
  // l15 group (covers all 64 keys of this wave's wn half)
  float* srow = sums + (((size_t)bh) << 11) + m0 + wm;
#pragma unroll
  for (int mf = 0; mf < 4; ++mf) {
#pragma unroll
    for (int r = 0; r < 4; ++r) {
      float ps = exp2v(acc[mf][0][r] - SHIFT2) + exp2v(acc[mf][1][r] - SHIFT2) +
                 exp2v(acc[mf][2][r] - SHIFT2) + exp2v(acc[mf][3][r] - SHIFT2);
      ps += __shfl_xor(ps, 1);
      ps += __shfl_xor(ps, 2);
      ps += __shfl_xor(ps, 4);
      ps += __shfl_xor(ps, 8);
      if (l15 == 0) atomicAdd(&srow[mf * 16 + l4 * 4 + r], ps);
    }
  }
}

// ---------------------------------------------------------------- attention pass 2
// Row sums precomputed. K staged in LDS (dbuf), Q/V fragments direct
// global->reg. p = 2^(s - c2); P transposed through wave-private LDS tile ->
// full-line nontemporal f32 stores; PV A-fragments rebuilt via cvt_pk.
__global__ __launch_bounds__(256) void attn_kernel(const u16* Qp, const u16* Kp,
                                                   const u16* VT, const float* sums,
                                                   float* attn, u16* ctx) {
  const int q0 = blockIdx.x * 64;
  const int h = blockIdx.y, b = blockIdx.z;
  const int tid = threadIdx.x, lane = tid & 63, w = tid >> 6;
  const int l15 = lane & 15, l4 = lane >> 4;
  const int lr = lane >> 3, lj = lane & 7;

  __shared__ __align__(16) char smem[32 * 1024];
  // Pf32: [wave][16 rows][256B] at 0..16K ; K dbuf at 16K + (t&1)*8K
  char* Pw = smem + w * 4096;

  const u16* Qbase = Qp + ((size_t)(b * L_ + q0 + w * 16) * D_MODEL_ + h * DH_);
  const u16* Kbase = Kp + ((size_t)(b * L_) * D_MODEL_ + h * DH_);
  const u16* Vb = VT + ((size_t)((b * H_ + h) * DH_) * L_);
  float* attnb = attn + ((size_t)(b * H_ + h)) * L_ * L_;

  auto stK = [&](int t) {
    const int c0 = t * 64, bsel = (t & 1) << 13;
    for (int c = w; c < 8; c += 4) {
      int r = c * 8 + lr, sj = lj ^ (r & 7);
      gl_lds16((const char*)(Kbase + (size_t)(c0 + r) * D_MODEL_) + sj * 16,
               smem + 16384 + bsel + c * 1024);
    }
  };

  bf16x8 qa[2];
#pragma unroll
  for (int ksub = 0; ksub < 2; ++ksub)
    qa[ksub] = *(const bf16x8*)(Qbase + (size_t)l15 * D_MODEL_ + (ksub * 4 + l4) * 8);

  // per-lane normalizer from precomputed sums (lane's q-row = l15)
  const float c2 =
      SHIFT2 + __log2f(sums[(((size_t)(b * H_ + h)) << 11) + q0 + w * 16 + l15]);

  stK(0);

  f32x4 cacc[4];
#pragma unroll
  for (int i = 0; i < 4; ++i) cacc[i] = f32x4{0.f, 0.f, 0.f, 0.f};

  const int swz = l15 & 7;
  float* awave = attnb + (size_t)(q0 + w * 16) * L_;
  __syncthreads();

  for (int t = 0; t < 32; ++t) {
    const int c0 = t * 64;
    if (t < 31) stK(t + 1);
    // V fragments for THIS tile, issued early (consumed at PV)
    bf16x8 va[2][4];
#pragma unroll
    for (int ksub = 0; ksub < 2; ++ksub)
#pragma unroll
      for (int df = 0; df < 4; ++df)
        va[ksub][df] = *(const bf16x8*)(Vb + (size_t)(df * 16 + l15) * L_ + c0 +
                                        (ksub * 4 + l4) * 8);
    __builtin_amdgcn_sched_barrier(0);

    const char* Ks = smem + 16384 + ((t & 1) << 13);
    f32x4 s[4];
#pragma unroll
    for (int nf = 0; nf < 4; ++nf) s[nf] = f32x4{0.f, 0.f, 0.f, 0.f};
    __builtin_amdgcn_s_setprio(1);
#pragma unroll
    for (int ksub = 0; ksub < 2; ++ksub) {
      int j16 = ksub * 4 + l4;
      bf16x8 kb[4];
#pragma unroll
      for (int nf = 0; nf < 4; ++nf) {
        int r = nf * 16 + l15;
        kb[nf] = *(const bf16x8*)(Ks + r * 128 + ((j16 ^ (r & 7)) * 16));
      }
#pragma unroll
      for (int nf = 0; nf < 4; ++nf) s[nf] = mfma16(kb[nf], qa[ksub], s[nf]);
    }
    __builtin_amdgcn_s_setprio(0);

    // p = 2^(s - c2) -> Pf32 LDS (fragment layout, swizzled chunks)
#pragma unroll
    for (int nf = 0; nf < 4; ++nf) {
      f32x4 p4;
#pragma unroll
      for (int r = 0; r < 4; ++r) p4[r] = exp2v(s[nf][r] - c2);
      *(f32x4*)(Pw + l15 * 256 + (((nf * 4 + l4) ^ swz) * 16)) = p4;
    }
    // transposed read -> full-line nontemporal global stores
#pragma unroll
    for (int j = 0; j < 4; ++j) {
      int row = 4 * j + (lane >> 4);
      f32x4 v = *(const f32x4*)(Pw + row * 256 + (((lane & 15) ^ (row & 7)) * 16));
      __builtin_nontemporal_store(
          v, (f32x4*)(awave + (size_t)row * L_ + c0 + (lane & 15) * 4));
    }
    // PV: rebuild pa from Pf32 (pairs -> bf16), accumulate with direct-V regs
    __builtin_amdgcn_s_setprio(1);
#pragma unroll
    for (int ksub = 0; ksub < 2; ++ksub) {
      int cbase = (ksub * 4 + l4) * 2;
      f32x4 plo = *(const f32x4*)(Pw + l15 * 256 + ((cbase ^ swz) * 16));
      f32x4 phi = *(const f32x4*)(Pw + l15 * 256 + (((cbase + 1) ^ swz) * 16));
      union { u32x4 u; bf16x8 h; } pa;
      pa.u[0] = pkbf(plo[0], plo[1]);
      pa.u[1] = pkbf(plo[2], plo[3]);
      pa.u[2] = pkbf(phi[0], phi[1]);
      pa.u[3] = pkbf(phi[2], phi[3]);
#pragma unroll
      for (int df = 0; df < 4; ++df)
        cacc[df] = mfma16(pa.h, va[ksub][df], cacc[df]);
    }
    __builtin_amdgcn_s_setprio(0);
    if (t < 31) {
      asm volatile("s_waitcnt vmcnt(12)" ::: "memory");
      __builtin_amdgcn_s_barrier();
      __builtin_amdgcn_sched_barrier(0);
    }
  }

  // ctx write (bf16): row = q0 + w*16 + 4*l4 + r, col = h*64 + df*16 + l15
#pragma unroll
  for (int df = 0; df < 4; ++df) {
#pragma unroll
    for (int r = 0; r < 4; ++r) {
      int row = q0 + w * 16 + l4 * 4 + r;
      int col = h * DH_ + df * 16 + l15;
      ctx[(size_t)(b * L_ + row) * D_MODEL_ + col] = f2bf(cacc[df][r]);
    }
  }
}

// ---------------------------------------------------------------- launch
extern "C" void kernel_launch(void* const* d_in, const int* in_sizes, int n_in,
                              void* d_out, int out_size, void* d_ws, size_t ws_size,
                              hipStream_t stream) {
  const float* q = (const float*)d_in[0];
  const float* k = (const float*)d_in[1];
  const float* v = (const float*)d_in[2];
  const float* w_q = (const float*)d_in[3];
  const float* b_q = (const float*)d_in[4];
  const float* w_k = (const float*)d_in[5];
  const float* b_k = (const float*)d_in[6];
  const float* w_v = (const float*)d_in[7];
  const float* b_v = (const float*)d_in[8];
  const float* w_o = (const float*)d_in[9];
  const float* b_o = (const float*)d_in[10];

  float* out = (float*)d_out;
  float* attn = (float*)d_out + (size_t)B_ * L_ * D_MODEL_;

  const size_t MB = 1u << 20;
  char* ws = (char*)d_ws;
  u16* qb = (u16*)(ws + 0 * MB);
  u16* kb = (u16*)(ws + 8 * MB);    // reused as ctx(bf16) after QKV GEMM
  u16* vb = (u16*)(ws + 16 * MB);
  u16* wqb = (u16*)(ws + 24 * MB);
  u16* wkb = (u16*)(ws + 26 * MB);
  u16* wvb = (u16*)(ws + 28 * MB);
  u16* wob = (u16*)(ws + 30 * MB);
  u16* Qp = (u16*)(ws + 32 * MB);
  u16* Kp = (u16*)(ws + 40 * MB);
  u16* VT = (u16*)(ws + 48 * MB);
  float* sums = (float*)(ws + 56 * MB);   // B*H*L f32 = 256KB
  u16* ctx = kb;

  // 1. cast everything to bf16 (+ zero sums)
  CastArgs ca;
  ca.src[0] = q;   ca.dst[0] = qb;  ca.n8[0] = (B_ * L_ * D_MODEL_) / 8;
  ca.src[1] = k;   ca.dst[1] = kb;  ca.n8[1] = (B_ * L_ * D_MODEL_) / 8;
  ca.src[2] = v;   ca.dst[2] = vb;  ca.n8[2] = (B_ * L_ * D_MODEL_) / 8;
  ca.src[3] = w_q; ca.dst[3] = wqb; ca.n8[3] = (D_MODEL_ * D_MODEL_) / 8;
  ca.src[4] = w_k; ca.dst[4] = wkb; ca.n8[4] = (D_MODEL_ * D_MODEL_) / 8;
  ca.src[5] = w_v; ca.dst[5] = wvb; ca.n8[5] = (D_MODEL_ * D_MODEL_) / 8;
  ca.src[6] = w_o; ca.dst[6] = wob; ca.n8[6] = (D_MODEL_ * D_MODEL_) / 8;
  ca.src[7] = nullptr; ca.dst[7] = (u16*)sums; ca.n8[7] = (B_ * H_ * L_ * 4) / 16;
  cast_kernel<<<dim3(1024, 1, 8), 256, 0, stream>>>(ca);

  // 2. QKV projections. Q's alpha folds 1/8 (score scale) * log2(e) (base-2 exp domain).
  GemmArgs ga;
  ga.X[0] = qb;  ga.W[0] = wqb; ga.bias[0] = b_q; ga.out[0] = Qp; ga.alpha[0] = 0.125f * 1.44269504f; ga.mode[0] = 0;
  ga.X[1] = kb;  ga.W[1] = wkb; ga.bias[1] = b_k; ga.out[1] = Kp; ga.alpha[1] = 1.f;    ga.mode[1] = 0;
  ga.X[2] = vb;  ga.W[2] = wvb; ga.bias[2] = b_v; ga.out[2] = VT; ga.alpha[2] = 1.f;    ga.mode[2] = 2;
  gemm_bt<<<dim3(8, 32, 3), 256, 0, stream>>>(ga);

  // 3a. row sums of 2^(s-SHIFT2): 128x128 GEMM-tile structure
  sumexp_kernel<<<dim3(16, 16, 32), 256, 0, stream>>>(Qp, Kp, sums);

  // 3b. attention pass 2: normalized P out + ctx
  attn_kernel<<<dim3(32, 16, 2), 256, 0, stream>>>(Qp, Kp, VT, sums, attn, ctx);

  // 4. output projection (f32 out + bias)
  GemmArgs go;
  go.X[0] = ctx; go.W[0] = wob; go.bias[0] = b_o; go.out[0] = out; go.alpha[0] = 1.f; go.mode[0] = 1;
  go.X[1] = ctx; go.W[1] = wob; go.bias[1] = b_o; go.out[1] = out; go.alpha[1] = 1.f; go.mode[1] = 1;
  go.X[2] = ctx; go.W[2] = wob; go.bias[2] = b_o; go.out[2] = out; go.alpha[2] = 1.f; go.mode[2] = 1;
  gemm_bt<<<dim3(8, 32, 1), 256, 0, stream>>>(go);
}

// Round 16
// 271.988 us; speedup vs baseline: 1.2633x; 1.1179x over previous
//
#include <hip/hip_runtime.h>
#include <hip/hip_bf16.h>
#include <stdint.h>

#define DEV static __device__ __forceinline__

typedef float f32x4 __attribute__((ext_vector_type(4)));
typedef __bf16 bf16x8 __attribute__((ext_vector_type(8)));
typedef unsigned short u16x8 __attribute__((ext_vector_type(8)));
typedef unsigned short u16x4 __attribute__((ext_vector_type(4)));
typedef uint32_t u32x4 __attribute__((ext_vector_type(4)));
typedef unsigned short u16;

#define B_ 2
#define L_ 2048
#define D_MODEL_ 1024
#define H_ 16
#define DH_ 64

// shift in base-2 score domain: 8 (base-e) * log2(e)
#define SHIFT2 11.5415603f

DEV u16 f2bf(float f) {
  union { float f; uint32_t u; } v; v.f = f;
  uint32_t r = v.u + 0x7FFFu + ((v.u >> 16) & 1u);  // RNE
  return (u16)(r >> 16);
}

DEV float exp2v(float x) {
#if __has_builtin(__builtin_amdgcn_exp2f)
  return __builtin_amdgcn_exp2f(x);
#else
  float r;
  asm("v_exp_f32 %0, %1" : "=v"(r) : "v"(x));
  return r;
#endif
}

// pack two f32 -> u32 of 2x bf16 (lo = a, hi = b), RNE
DEV uint32_t pkbf(float a, float b) {
  __hip_bfloat162 h = __float22bfloat162_rn(float2{a, b});
  union { __hip_bfloat162 h; uint32_t u; } cv; cv.h = h;
  return cv.u;
}

DEV f32x4 mfma16(bf16x8 a, bf16x8 b, f32x4 c) {
  return __builtin_amdgcn_mfma_f32_16x16x32_bf16(a, b, c, 0, 0, 0);
}

// async global->LDS, 16B per lane. LDS dest = wave-uniform base + lane*16.
DEV void gl_lds16(const void* g, void* l) {
  __builtin_amdgcn_global_load_lds(
      (const __attribute__((address_space(1))) unsigned int*)g,
      (__attribute__((address_space(3))) unsigned int*)l, 16, 0, 0);
}

// ---------------------------------------------------------------- cast f32->bf16 (src==null -> zero fill)
struct CastArgs {
  const float* src[8];
  u16* dst[8];
  int n8[8];
};

__global__ __launch_bounds__(256) void cast_kernel(CastArgs a) {
  const int z = blockIdx.z;
  u16* d = a.dst[z];
  const int n8 = a.n8[z];
  const int stride = gridDim.x * blockDim.x;
  const float* s = a.src[z];
  if (s == nullptr) {
    for (int i = blockIdx.x * blockDim.x + threadIdx.x; i < n8; i += stride)
      *((u16x8*)d + i) = u16x8{0, 0, 0, 0, 0, 0, 0, 0};
    return;
  }
  for (int i = blockIdx.x * blockDim.x + threadIdx.x; i < n8; i += stride) {
    const float4* sp = (const float4*)s + (size_t)i * 2;
    float4 x0 = sp[0], x1 = sp[1];
    u16x8 o;
    o[0] = f2bf(x0.x); o[1] = f2bf(x0.y); o[2] = f2bf(x0.z); o[3] = f2bf(x0.w);
    o[4] = f2bf(x1.x); o[5] = f2bf(x1.y); o[6] = f2bf(x1.z); o[7] = f2bf(x1.w);
    *((u16x8*)d + i) = o;
  }
}

// ---------------------------------------------------------------- GEMM  out = (X @ W^T + bias) * alpha
// mode 0: bf16 row-major out; mode 1: f32 row-major out; mode 2: VT bf16 out [B][H][DH][L]
#define GM 4096
#define GN 1024
#define GK 1024

struct GemmArgs {
  const u16* X[3];
  const u16* W[3];
  const float* bias[3];
  void* out[3];
  float alpha[3];
  int mode[3];
};

__global__ __launch_bounds__(256) void gemm_bt(GemmArgs g) {
  const int z = blockIdx.z;
  const u16* X = g.X[z];
  const u16* W = g.W[z];
  const float* bias = g.bias[z];
  const float alpha = g.alpha[z];
  const int mode = g.mode[z];
  const int m0 = blockIdx.y * 128, n0 = blockIdx.x * 128;

  __shared__ __align__(16) char smem[32 * 1024];
  char* As = smem;            // [128 rows][128B] XOR-swizzled by ((r&7)<<4)
  char* Bs = smem + 16 * 1024;

  const int tid = threadIdx.x;
  const int lane = tid & 63, w = tid >> 6;
  const int l15 = lane & 15, l4 = lane >> 4;
  const int wm = (w >> 1) * 64, wn = (w & 1) * 64;

  f32x4 acc[4][4];
#pragma unroll
  for (int i = 0; i < 4; ++i)
#pragma unroll
    for (int j = 0; j < 4; ++j) acc[i][j] = f32x4{0.f, 0.f, 0.f, 0.f};

  for (int ks = 0; ks < GK; ks += 64) {
    __syncthreads();
    for (int c = w; c < 16; c += 4) {
      int r = c * 8 + (lane >> 3);
      int j = lane & 7;
      int sj = j ^ (r & 7);
      gl_lds16((const char*)(X + (size_t)(m0 + r) * GK + ks) + sj * 16, As + c * 1024);
      gl_lds16((const char*)(W + (size_t)(n0 + r) * GK + ks) + sj * 16, Bs + c * 1024);
    }
    __syncthreads();
#pragma unroll
    for (int ksub = 0; ksub < 2; ++ksub) {
      bf16x8 af[4], bfr[4];
#pragma unroll
      for (int mf = 0; mf < 4; ++mf) {
        int r = wm + mf * 16 + l15;
        int j16 = ksub * 4 + l4;
        af[mf] = *(const bf16x8*)(As + r * 128 + ((j16 ^ (r & 7)) * 16));
      }
#pragma unroll
      for (int nf = 0; nf < 4; ++nf) {
        int r = wn + nf * 16 + l15;
        int j16 = ksub * 4 + l4;
        bfr[nf] = *(const bf16x8*)(Bs + r * 128 + ((j16 ^ (r & 7)) * 16));
      }
#pragma unroll
      for (int mf = 0; mf < 4; ++mf)
#pragma unroll
        for (int nf = 0; nf < 4; ++nf) acc[mf][nf] = mfma16(af[mf], bfr[nf], acc[mf][nf]);
    }
  }

  if (mode == 2) {
    // V projection -> VT [B][H][DH][L]: b=m>>11, l=m&2047, h=n>>6, dh=n&63
    u16* base = (u16*)g.out[z];
#pragma unroll
    for (int nf = 0; nf < 4; ++nf) {
      int n = n0 + wn + nf * 16 + l15;
      float bv = bias[n];
#pragma unroll
      for (int mf = 0; mf < 4; ++mf) {
        int m = m0 + wm + mf * 16 + l4 * 4;
        u16x4 pk;
#pragma unroll
        for (int r = 0; r < 4; ++r) pk[r] = f2bf((acc[mf][nf][r] + bv) * alpha);
        size_t off = (((size_t)(m >> 11) * H_ + (n >> 6)) * DH_ + (n & 63)) * (size_t)L_ + (m & 2047);
        *(u16x4*)(base + off) = pk;
      }
    }
  } else {
#pragma unroll
    for (int nf = 0; nf < 4; ++nf) {
      int n = n0 + wn + nf * 16 + l15;
      float bv = bias[n];
#pragma unroll
      for (int mf = 0; mf < 4; ++mf) {
#pragma unroll
        for (int r = 0; r < 4; ++r) {
          int m = m0 + wm + mf * 16 + l4 * 4 + r;
          float val = (acc[mf][nf][r] + bv) * alpha;
          if (mode == 1)
            ((float*)g.out[z])[(size_t)m * GN + n] = val;
          else
            ((u16*)g.out[z])[(size_t)m * GN + n] = f2bf(val);
        }
      }
    }
  }
}

// ---------------------------------------------------------------- sum-exp kernel (R9 structure — best known)
// sums[bh][row] += sum over 512-key chunk of 2^(s - SHIFT2).
__global__ __launch_bounds__(256) void sumexp_kernel(const u16* Qp, const u16* Kp,
                                                     float* sums) {
  const int q0 = blockIdx.x * 64;
  const int kc0 = blockIdx.y * 512;
  const int bh = blockIdx.z;
  const int b = bh >> 4, h = bh & 15;
  const int tid = threadIdx.x, lane = tid & 63, w = tid >> 6;
  const int l15 = lane & 15, l4 = lane >> 4;
  const int lr = lane >> 3, lj = lane & 7;

  __shared__ __align__(16) char smem[16 * 1024];  // K dbuf 8K x2

  const u16* Qbase = Qp + ((size_t)(b * L_ + q0 + w * 16) * D_MODEL_ + h * DH_);
  const u16* Kbase = Kp + ((size_t)(b * L_ + kc0) * D_MODEL_ + h * DH_);

  auto stK = [&](int t) {
    const int c0 = t * 64, bsel = (t & 1) << 13;
    for (int c = w; c < 8; c += 4) {
      int r = c * 8 + lr, sj = lj ^ (r & 7);
      gl_lds16((const char*)(Kbase + (size_t)(c0 + r) * D_MODEL_) + sj * 16,
               smem + bsel + c * 1024);
    }
  };

  bf16x8 qa[2];
#pragma unroll
  for (int ksub = 0; ksub < 2; ++ksub)
    qa[ksub] = *(const bf16x8*)(Qbase + (size_t)l15 * D_MODEL_ + (ksub * 4 + l4) * 8);

  stK(0);
  __syncthreads();

  float ssum = 0.f;
  for (int t = 0; t < 8; ++t) {
    if (t < 7) stK(t + 1);
    const char* Ks = smem + ((t & 1) << 13);
    f32x4 s[4];
#pragma unroll
    for (int nf = 0; nf < 4; ++nf) s[nf] = f32x4{0.f, 0.f, 0.f, 0.f};
#pragma unroll
    for (int ksub = 0; ksub < 2; ++ksub) {
      int j16 = ksub * 4 + l4;
      bf16x8 kb[4];
#pragma unroll
      for (int nf = 0; nf < 4; ++nf) {
        int r = nf * 16 + l15;
        kb[nf] = *(const bf16x8*)(Ks + r * 128 + ((j16 ^ (r & 7)) * 16));
      }
#pragma unroll
      for (int nf = 0; nf < 4; ++nf) s[nf] = mfma16(kb[nf], qa[ksub], s[nf]);
    }
#pragma unroll
    for (int nf = 0; nf < 4; ++nf)
#pragma unroll
      for (int r = 0; r < 4; ++r) ssum += exp2v(s[nf][r] - SHIFT2);
    __syncthreads();
  }

  // merge the 4 l4-groups (different keys, same q-row l15)
  ssum += __shfl_xor(ssum, 16);
  ssum += __shfl_xor(ssum, 32);
  if (lane < 16)
    atomicAdd(&sums[((size_t)bh << 11) + q0 + w * 16 + lane], ssum);
}

// ---------------------------------------------------------------- attention pass 2 (R9 + XCD-contiguous writes)
// Flat grid 1024; lid = (bid&7)*128 + bid>>3 gives each XCD 128 CONSECUTIVE
// logical blocks = one contiguous 64MB span of the attn buffer, so each
// XCD's L2 streams writes sequentially to its own address range.
// Row sums precomputed. K staged in LDS (dbuf), Q/V fragments direct
// global->reg. p = 2^(s - c2); P transposed through wave-private LDS tile ->
// full-line nontemporal f32 stores; PV A-fragments rebuilt via cvt_pk.
__global__ __launch_bounds__(256) void attn_kernel(const u16* Qp, const u16* Kp,
                                                   const u16* VT, const float* sums,
                                                   float* attn, u16* ctx) {
  const int bid = blockIdx.x;
  const int lid = (bid & 7) * 128 + (bid >> 3);  // bijective: 1024 % 8 == 0
  const int q0 = (lid & 31) * 64;
  const int h = (lid >> 5) & 15;
  const int b = lid >> 9;
  const int tid = threadIdx.x, lane = tid & 63, w = tid >> 6;
  const int l15 = lane & 15, l4 = lane >> 4;
  const int lr = lane >> 3, lj = lane & 7;

  __shared__ __align__(16) char smem[32 * 1024];
  // Pf32: [wave][16 rows][256B] at 0..16K ; K dbuf at 16K + (t&1)*8K
  char* Pw = smem + w * 4096;

  const u16* Qbase = Qp + ((size_t)(b * L_ + q0 + w * 16) * D_MODEL_ + h * DH_);
  const u16* Kbase = Kp + ((size_t)(b * L_) * D_MODEL_ + h * DH_);
  const u16* Vb = VT + ((size_t)((b * H_ + h) * DH_) * L_);
  float* attnb = attn + ((size_t)(b * H_ + h)) * L_ * L_;

  auto stK = [&](int t) {
    const int c0 = t * 64, bsel = (t & 1) << 13;
    for (int c = w; c < 8; c += 4) {
      int r = c * 8 + lr, sj = lj ^ (r & 7);
      gl_lds16((const char*)(Kbase + (size_t)(c0 + r) * D_MODEL_) + sj * 16,
               smem + 16384 + bsel + c * 1024);
    }
  };

  bf16x8 qa[2];
#pragma unroll
  for (int ksub = 0; ksub < 2; ++ksub)
    qa[ksub] = *(const bf16x8*)(Qbase + (size_t)l15 * D_MODEL_ + (ksub * 4 + l4) * 8);

  // per-lane normalizer from precomputed sums (lane's q-row = l15)
  const float c2 =
      SHIFT2 + __log2f(sums[(((size_t)(b * H_ + h)) << 11) + q0 + w * 16 + l15]);

  stK(0);

  f32x4 cacc[4];
#pragma unroll
  for (int i = 0; i < 4; ++i) cacc[i] = f32x4{0.f, 0.f, 0.f, 0.f};

  const int swz = l15 & 7;
  float* awave = attnb + (size_t)(q0 + w * 16) * L_;
  __syncthreads();

  for (int t = 0; t < 32; ++t) {
    const int c0 = t * 64;
    if (t < 31) stK(t + 1);
    // V fragments for THIS tile, issued early (consumed at PV)
    bf16x8 va[2][4];
#pragma unroll
    for (int ksub = 0; ksub < 2; ++ksub)
#pragma unroll
      for (int df = 0; df < 4; ++df)
        va[ksub][df] = *(const bf16x8*)(Vb + (size_t)(df * 16 + l15) * L_ + c0 +
                                        (ksub * 4 + l4) * 8);
    __builtin_amdgcn_sched_barrier(0);

    const char* Ks = smem + 16384 + ((t & 1) << 13);
    f32x4 s[4];
#pragma unroll
    for (int nf = 0; nf < 4; ++nf) s[nf] = f32x4{0.f, 0.f, 0.f, 0.f};
    __builtin_amdgcn_s_setprio(1);
#pragma unroll
    for (int ksub = 0; ksub < 2; ++ksub) {
      int j16 = ksub * 4 + l4;
      bf16x8 kb[4];
#pragma unroll
      for (int nf = 0; nf < 4; ++nf) {
        int r = nf * 16 + l15;
        kb[nf] = *(const bf16x8*)(Ks + r * 128 + ((j16 ^ (r & 7)) * 16));
      }
#pragma unroll
      for (int nf = 0; nf < 4; ++nf) s[nf] = mfma16(kb[nf], qa[ksub], s[nf]);
    }
    __builtin_amdgcn_s_setprio(0);

    // p = 2^(s - c2) -> Pf32 LDS (fragment layout, swizzled chunks)
#pragma unroll
    for (int nf = 0; nf < 4; ++nf) {
      f32x4 p4;
#pragma unroll
      for (int r = 0; r < 4; ++r) p4[r] = exp2v(s[nf][r] - c2);
      *(f32x4*)(Pw + l15 * 256 + (((nf * 4 + l4) ^ swz) * 16)) = p4;
    }
    // transposed read -> full-line nontemporal global stores
#pragma unroll
    for (int j = 0; j < 4; ++j) {
      int row = 4 * j + (lane >> 4);
      f32x4 v = *(const f32x4*)(Pw + row * 256 + (((lane & 15) ^ (row & 7)) * 16));
      __builtin_nontemporal_store(
          v, (f32x4*)(awave + (size_t)row * L_ + c0 + (lane & 15) * 4));
    }
    // PV: rebuild pa from Pf32 (pairs -> bf16), accumulate with direct-V regs
    __builtin_amdgcn_s_setprio(1);
#pragma unroll
    for (int ksub = 0; ksub < 2; ++ksub) {
      int cbase = (ksub * 4 + l4) * 2;
      f32x4 plo = *(const f32x4*)(Pw + l15 * 256 + ((cbase ^ swz) * 16));
      f32x4 phi = *(const f32x4*)(Pw + l15 * 256 + (((cbase + 1) ^ swz) * 16));
      union { u32x4 u; bf16x8 h; } pa;
      pa.u[0] = pkbf(plo[0], plo[1]);
      pa.u[1] = pkbf(plo[2], plo[3]);
      pa.u[2] = pkbf(phi[0], phi[1]);
      pa.u[3] = pkbf(phi[2], phi[3]);
#pragma unroll
      for (int df = 0; df < 4; ++df)
        cacc[df] = mfma16(pa.h, va[ksub][df], cacc[df]);
    }
    __builtin_amdgcn_s_setprio(0);
    if (t < 31) {
      asm volatile("s_waitcnt vmcnt(12)" ::: "memory");
      __builtin_amdgcn_s_barrier();
      __builtin_amdgcn_sched_barrier(0);
    }
  }

  // ctx write (bf16): row = q0 + w*16 + 4*l4 + r, col = h*64 + df*16 + l15
#pragma unroll
  for (int df = 0; df < 4; ++df) {
#pragma unroll
    for (int r = 0; r < 4; ++r) {
      int row = q0 + w * 16 + l4 * 4 + r;
      int col = h * DH_ + df * 16 + l15;
      ctx[(size_t)(b * L_ + row) * D_MODEL_ + col] = f2bf(cacc[df][r]);
    }
  }
}

// ---------------------------------------------------------------- launch
extern "C" void kernel_launch(void* const* d_in, const int* in_sizes, int n_in,
                              void* d_out, int out_size, void* d_ws, size_t ws_size,
                              hipStream_t stream) {
  const float* q = (const float*)d_in[0];
  const float* k = (const float*)d_in[1];
  const float* v = (const float*)d_in[2];
  const float* w_q = (const float*)d_in[3];
  const float* b_q = (const float*)d_in[4];
  const float* w_k = (const float*)d_in[5];
  const float* b_k = (const float*)d_in[6];
  const float* w_v = (const float*)d_in[7];
  const float* b_v = (const float*)d_in[8];
  const float* w_o = (const float*)d_in[9];
  const float* b_o = (const float*)d_in[10];

  float* out = (float*)d_out;
  float* attn = (float*)d_out + (size_t)B_ * L_ * D_MODEL_;

  const size_t MB = 1u << 20;
  char* ws = (char*)d_ws;
  u16* qb = (u16*)(ws + 0 * MB);
  u16* kb = (u16*)(ws + 8 * MB);    // reused as ctx(bf16) after QKV GEMM
  u16* vb = (u16*)(ws + 16 * MB);
  u16* wqb = (u16*)(ws + 24 * MB);
  u16* wkb = (u16*)(ws + 26 * MB);
  u16* wvb = (u16*)(ws + 28 * MB);
  u16* wob = (u16*)(ws + 30 * MB);
  u16* Qp = (u16*)(ws + 32 * MB);
  u16* Kp = (u16*)(ws + 40 * MB);
  u16* VT = (u16*)(ws + 48 * MB);
  float* sums = (float*)(ws + 56 * MB);   // B*H*L f32 = 256KB
  u16* ctx = kb;

  // 1. cast everything to bf16 (+ zero sums)
  CastArgs ca;
  ca.src[0] = q;   ca.dst[0] = qb;  ca.n8[0] = (B_ * L_ * D_MODEL_) / 8;
  ca.src[1] = k;   ca.dst[1] = kb;  ca.n8[1] = (B_ * L_ * D_MODEL_) / 8;
  ca.src[2] = v;   ca.dst[2] = vb;  ca.n8[2] = (B_ * L_ * D_MODEL_) / 8;
  ca.src[3] = w_q; ca.dst[3] = wqb; ca.n8[3] = (D_MODEL_ * D_MODEL_) / 8;
  ca.src[4] = w_k; ca.dst[4] = wkb; ca.n8[4] = (D_MODEL_ * D_MODEL_) / 8;
  ca.src[5] = w_v; ca.dst[5] = wvb; ca.n8[5] = (D_MODEL_ * D_MODEL_) / 8;
  ca.src[6] = w_o; ca.dst[6] = wob; ca.n8[6] = (D_MODEL_ * D_MODEL_) / 8;
  ca.src[7] = nullptr; ca.dst[7] = (u16*)sums; ca.n8[7] = (B_ * H_ * L_ * 4) / 16;
  cast_kernel<<<dim3(1024, 1, 8), 256, 0, stream>>>(ca);

  // 2. QKV projections. Q's alpha folds 1/8 (score scale) * log2(e) (base-2 exp domain).
  GemmArgs ga;
  ga.X[0] = qb;  ga.W[0] = wqb; ga.bias[0] = b_q; ga.out[0] = Qp; ga.alpha[0] = 0.125f * 1.44269504f; ga.mode[0] = 0;
  ga.X[1] = kb;  ga.W[1] = wkb; ga.bias[1] = b_k; ga.out[1] = Kp; ga.alpha[1] = 1.f;    ga.mode[1] = 0;
  ga.X[2] = vb;  ga.W[2] = wvb; ga.bias[2] = b_v; ga.out[2] = VT; ga.alpha[2] = 1.f;    ga.mode[2] = 2;
  gemm_bt<<<dim3(8, 32, 3), 256, 0, stream>>>(ga);

  // 3a. row sums of 2^(s-SHIFT2)
  sumexp_kernel<<<dim3(32, 4, 32), 256, 0, stream>>>(Qp, Kp, sums);

  // 3b. attention pass 2: XCD-contiguous write spans
  attn_kernel<<<dim3(1024, 1, 1), 256, 0, stream>>>(Qp, Kp, VT, sums, attn, ctx);

  // 4. output projection (f32 out + bias)
  GemmArgs go;
  go.X[0] = ctx; go.W[0] = wob; go.bias[0] = b_o; go.out[0] = out; go.alpha[0] = 1.f; go.mode[0] = 1;
  go.X[1] = ctx; go.W[1] = wob; go.bias[1] = b_o; go.out[1] = out; go.alpha[1] = 1.f; go.mode[1] = 1;
  go.X[2] = ctx; go.W[2] = wob; go.bias[2] = b_o; go.out[2] = out; go.alpha[2] = 1.f; go.mode[2] = 1;
  gemm_bt<<<dim3(8, 32, 1), 256, 0, stream>>>(go);
}

// Round 17
// 245.755 us; speedup vs baseline: 1.3982x; 1.1067x over previous
//
#include <hip/hip_runtime.h>
#include <hip/hip_bf16.h>
#include <stdint.h>

#define DEV static __device__ __forceinline__

typedef float f32x4 __attribute__((ext_vector_type(4)));
typedef __bf16 bf16x8 __attribute__((ext_vector_type(8)));
typedef unsigned short u16x8 __attribute__((ext_vector_type(8)));
typedef unsigned short u16x4 __attribute__((ext_vector_type(4)));
typedef uint32_t u32x4 __attribute__((ext_vector_type(4)));
typedef unsigned short u16;

#define B_ 2
#define L_ 2048
#define D_MODEL_ 1024
#define H_ 16
#define DH_ 64

// shift in base-2 score domain: 8 (base-e) * log2(e)
#define SHIFT2 11.5415603f

DEV u16 f2bf(float f) {
  union { float f; uint32_t u; } v; v.f = f;
  uint32_t r = v.u + 0x7FFFu + ((v.u >> 16) & 1u);  // RNE
  return (u16)(r >> 16);
}

DEV float exp2v(float x) {
#if __has_builtin(__builtin_amdgcn_exp2f)
  return __builtin_amdgcn_exp2f(x);
#else
  float r;
  asm("v_exp_f32 %0, %1" : "=v"(r) : "v"(x));
  return r;
#endif
}

// pack two f32 -> u32 of 2x bf16 (lo = a, hi = b), RNE
DEV uint32_t pkbf(float a, float b) {
  __hip_bfloat162 h = __float22bfloat162_rn(float2{a, b});
  union { __hip_bfloat162 h; uint32_t u; } cv; cv.h = h;
  return cv.u;
}

DEV f32x4 mfma16(bf16x8 a, bf16x8 b, f32x4 c) {
  return __builtin_amdgcn_mfma_f32_16x16x32_bf16(a, b, c, 0, 0, 0);
}

// async global->LDS, 16B per lane. LDS dest = wave-uniform base + lane*16.
DEV void gl_lds16(const void* g, void* l) {
  __builtin_amdgcn_global_load_lds(
      (const __attribute__((address_space(1))) unsigned int*)g,
      (__attribute__((address_space(3))) unsigned int*)l, 16, 0, 0);
}

// ---------------------------------------------------------------- cast f32->bf16 (src==null -> zero fill)
struct CastArgs {
  const float* src[8];
  u16* dst[8];
  int n8[8];
};

__global__ __launch_bounds__(256) void cast_kernel(CastArgs a) {
  const int z = blockIdx.z;
  u16* d = a.dst[z];
  const int n8 = a.n8[z];
  const int stride = gridDim.x * blockDim.x;
  const float* s = a.src[z];
  if (s == nullptr) {
    for (int i = blockIdx.x * blockDim.x + threadIdx.x; i < n8; i += stride)
      *((u16x8*)d + i) = u16x8{0, 0, 0, 0, 0, 0, 0, 0};
    return;
  }
  for (int i = blockIdx.x * blockDim.x + threadIdx.x; i < n8; i += stride) {
    const float4* sp = (const float4*)s + (size_t)i * 2;
    float4 x0 = sp[0], x1 = sp[1];
    u16x8 o;
    o[0] = f2bf(x0.x); o[1] = f2bf(x0.y); o[2] = f2bf(x0.z); o[3] = f2bf(x0.w);
    o[4] = f2bf(x1.x); o[5] = f2bf(x1.y); o[6] = f2bf(x1.z); o[7] = f2bf(x1.w);
    *((u16x8*)d + i) = o;
  }
}

// ---------------------------------------------------------------- GEMM  out = (X @ W^T + bias) * alpha
// mode 0: bf16 row-major out; mode 1: f32 row-major out;
// mode 2: V fragment-order out VF[bh][tile32][frag8][lane64][8] (bf16)
#define GM 4096
#define GN 1024
#define GK 1024

struct GemmArgs {
  const u16* X[3];
  const u16* W[3];
  const float* bias[3];
  void* out[3];
  float alpha[3];
  int mode[3];
};

__global__ __launch_bounds__(256) void gemm_bt(GemmArgs g) {
  const int z = blockIdx.z;
  const u16* X = g.X[z];
  const u16* W = g.W[z];
  const float* bias = g.bias[z];
  const float alpha = g.alpha[z];
  const int mode = g.mode[z];
  const int m0 = blockIdx.y * 128, n0 = blockIdx.x * 128;

  __shared__ __align__(16) char smem[32 * 1024];
  char* As = smem;            // [128 rows][128B] XOR-swizzled by ((r&7)<<4)
  char* Bs = smem + 16 * 1024;

  const int tid = threadIdx.x;
  const int lane = tid & 63, w = tid >> 6;
  const int l15 = lane & 15, l4 = lane >> 4;
  const int wm = (w >> 1) * 64, wn = (w & 1) * 64;

  f32x4 acc[4][4];
#pragma unroll
  for (int i = 0; i < 4; ++i)
#pragma unroll
    for (int j = 0; j < 4; ++j) acc[i][j] = f32x4{0.f, 0.f, 0.f, 0.f};

  for (int ks = 0; ks < GK; ks += 64) {
    __syncthreads();
    for (int c = w; c < 16; c += 4) {
      int r = c * 8 + (lane >> 3);
      int j = lane & 7;
      int sj = j ^ (r & 7);
      gl_lds16((const char*)(X + (size_t)(m0 + r) * GK + ks) + sj * 16, As + c * 1024);
      gl_lds16((const char*)(W + (size_t)(n0 + r) * GK + ks) + sj * 16, Bs + c * 1024);
    }
    __syncthreads();
#pragma unroll
    for (int ksub = 0; ksub < 2; ++ksub) {
      bf16x8 af[4], bfr[4];
#pragma unroll
      for (int mf = 0; mf < 4; ++mf) {
        int r = wm + mf * 16 + l15;
        int j16 = ksub * 4 + l4;
        af[mf] = *(const bf16x8*)(As + r * 128 + ((j16 ^ (r & 7)) * 16));
      }
#pragma unroll
      for (int nf = 0; nf < 4; ++nf) {
        int r = wn + nf * 16 + l15;
        int j16 = ksub * 4 + l4;
        bfr[nf] = *(const bf16x8*)(Bs + r * 128 + ((j16 ^ (r & 7)) * 16));
      }
#pragma unroll
      for (int mf = 0; mf < 4; ++mf)
#pragma unroll
        for (int nf = 0; nf < 4; ++nf) acc[mf][nf] = mfma16(af[mf], bfr[nf], acc[mf][nf]);
    }
  }

  if (mode == 2) {
    // V projection -> fragment-order VF (bf16):
    //   value (dh = n&63, l = m&2047, b = m>>11, h = n>>6)
    //   t = l>>6; chunk c = (l&63)>>3 (ksub = c>>2, fl4 = c&3); e = l&7
    //   off = ((bh*32 + t)*8 + (c>>2)*4 + (n&63)>>4)*512 + ((c&3)*16 + (n&15))*8 + e
    u16* base = (u16*)g.out[z];
#pragma unroll
    for (int nf = 0; nf < 4; ++nf) {
      int n = n0 + wn + nf * 16 + l15;
      float bv = bias[n];
      int df = (n & 63) >> 4, fl15 = n & 15, hh = n >> 6;
#pragma unroll
      for (int mf = 0; mf < 4; ++mf) {
        int m = m0 + wm + mf * 16 + l4 * 4;
        u16x4 pk;
#pragma unroll
        for (int r = 0; r < 4; ++r) pk[r] = f2bf((acc[mf][nf][r] + bv) * alpha);
        int lg = m & 2047, bb = m >> 11;
        int t = lg >> 6, lc = lg & 63;
        int c = lc >> 3, e = lc & 7;
        size_t off = ((((size_t)(bb * H_ + hh) * 32 + t) * 8 + (c >> 2) * 4 + df) * 512) +
                     ((c & 3) * 16 + fl15) * 8 + e;
        *(u16x4*)(base + off) = pk;
      }
    }
  } else {
#pragma unroll
    for (int nf = 0; nf < 4; ++nf) {
      int n = n0 + wn + nf * 16 + l15;
      float bv = bias[n];
#pragma unroll
      for (int mf = 0; mf < 4; ++mf) {
#pragma unroll
        for (int r = 0; r < 4; ++r) {
          int m = m0 + wm + mf * 16 + l4 * 4 + r;
          float val = (acc[mf][nf][r] + bv) * alpha;
          if (mode == 1)
            ((float*)g.out[z])[(size_t)m * GN + n] = val;
          else
            ((u16*)g.out[z])[(size_t)m * GN + n] = f2bf(val);
        }
      }
    }
  }
}

// ---------------------------------------------------------------- sum-exp kernel (R9 structure — best known)
// sums[bh][row] += sum over 512-key chunk of 2^(s - SHIFT2).
__global__ __launch_bounds__(256) void sumexp_kernel(const u16* Qp, const u16* Kp,
                                                     float* sums) {
  const int q0 = blockIdx.x * 64;
  const int kc0 = blockIdx.y * 512;
  const int bh = blockIdx.z;
  const int b = bh >> 4, h = bh & 15;
  const int tid = threadIdx.x, lane = tid & 63, w = tid >> 6;
  const int l15 = lane & 15, l4 = lane >> 4;
  const int lr = lane >> 3, lj = lane & 7;

  __shared__ __align__(16) char smem[16 * 1024];  // K dbuf 8K x2

  const u16* Qbase = Qp + ((size_t)(b * L_ + q0 + w * 16) * D_MODEL_ + h * DH_);
  const u16* Kbase = Kp + ((size_t)(b * L_ + kc0) * D_MODEL_ + h * DH_);

  auto stK = [&](int t) {
    const int c0 = t * 64, bsel = (t & 1) << 13;
    for (int c = w; c < 8; c += 4) {
      int r = c * 8 + lr, sj = lj ^ (r & 7);
      gl_lds16((const char*)(Kbase + (size_t)(c0 + r) * D_MODEL_) + sj * 16,
               smem + bsel + c * 1024);
    }
  };

  bf16x8 qa[2];
#pragma unroll
  for (int ksub = 0; ksub < 2; ++ksub)
    qa[ksub] = *(const bf16x8*)(Qbase + (size_t)l15 * D_MODEL_ + (ksub * 4 + l4) * 8);

  stK(0);
  __syncthreads();

  float ssum = 0.f;
  for (int t = 0; t < 8; ++t) {
    if (t < 7) stK(t + 1);
    const char* Ks = smem + ((t & 1) << 13);
    f32x4 s[4];
#pragma unroll
    for (int nf = 0; nf < 4; ++nf) s[nf] = f32x4{0.f, 0.f, 0.f, 0.f};
#pragma unroll
    for (int ksub = 0; ksub < 2; ++ksub) {
      int j16 = ksub * 4 + l4;
      bf16x8 kb[4];
#pragma unroll
      for (int nf = 0; nf < 4; ++nf) {
        int r = nf * 16 + l15;
        kb[nf] = *(const bf16x8*)(Ks + r * 128 + ((j16 ^ (r & 7)) * 16));
      }
#pragma unroll
      for (int nf = 0; nf < 4; ++nf) s[nf] = mfma16(kb[nf], qa[ksub], s[nf]);
    }
#pragma unroll
    for (int nf = 0; nf < 4; ++nf)
#pragma unroll
      for (int r = 0; r < 4; ++r) ssum += exp2v(s[nf][r] - SHIFT2);
    __syncthreads();
  }

  // merge the 4 l4-groups (different keys, same q-row l15)
  ssum += __shfl_xor(ssum, 16);
  ssum += __shfl_xor(ssum, 32);
  if (lane < 16)
    atomicAdd(&sums[((size_t)bh << 11) + q0 + w * 16 + lane], ssum);
}

// ---------------------------------------------------------------- attention pass 2
// R16 best + fragment-order V: va loads are 64 lanes x 16B CONTIGUOUS (1KB,
// 8 lines per instruction instead of 16 scattered lines) — removes TA
// multi-line serialization. XCD-contiguous write spans retained.
__global__ __launch_bounds__(256) void attn_kernel(const u16* Qp, const u16* Kp,
                                                   const u16* VF, const float* sums,
                                                   float* attn, u16* ctx) {
  const int bid = blockIdx.x;
  const int lid = (bid & 7) * 128 + (bid >> 3);  // bijective: 1024 % 8 == 0
  const int q0 = (lid & 31) * 64;
  const int h = (lid >> 5) & 15;
  const int b = lid >> 9;
  const int tid = threadIdx.x, lane = tid & 63, w = tid >> 6;
  const int l15 = lane & 15, l4 = lane >> 4;
  const int lr = lane >> 3, lj = lane & 7;

  __shared__ __align__(16) char smem[32 * 1024];
  // Pf32: [wave][16 rows][256B] at 0..16K ; K dbuf at 16K + (t&1)*8K
  char* Pw = smem + w * 4096;

  const u16* Qbase = Qp + ((size_t)(b * L_ + q0 + w * 16) * D_MODEL_ + h * DH_);
  const u16* Kbase = Kp + ((size_t)(b * L_) * D_MODEL_ + h * DH_);
  const u16* Vb = VF + ((size_t)(b * H_ + h) * 32) * 4096;  // per-head fragment bank
  float* attnb = attn + ((size_t)(b * H_ + h)) * L_ * L_;

  auto stK = [&](int t) {
    const int c0 = t * 64, bsel = (t & 1) << 13;
    for (int c = w; c < 8; c += 4) {
      int r = c * 8 + lr, sj = lj ^ (r & 7);
      gl_lds16((const char*)(Kbase + (size_t)(c0 + r) * D_MODEL_) + sj * 16,
               smem + 16384 + bsel + c * 1024);
    }
  };

  bf16x8 qa[2];
#pragma unroll
  for (int ksub = 0; ksub < 2; ++ksub)
    qa[ksub] = *(const bf16x8*)(Qbase + (size_t)l15 * D_MODEL_ + (ksub * 4 + l4) * 8);

  // per-lane normalizer from precomputed sums (lane's q-row = l15)
  const float c2 =
      SHIFT2 + __log2f(sums[(((size_t)(b * H_ + h)) << 11) + q0 + w * 16 + l15]);

  stK(0);

  f32x4 cacc[4];
#pragma unroll
  for (int i = 0; i < 4; ++i) cacc[i] = f32x4{0.f, 0.f, 0.f, 0.f};

  const int swz = l15 & 7;
  float* awave = attnb + (size_t)(q0 + w * 16) * L_;
  __syncthreads();

  for (int t = 0; t < 32; ++t) {
    const int c0 = t * 64;
    if (t < 31) stK(t + 1);
    // V fragments for THIS tile — fully coalesced 1KB loads from VF
    const u16* Vt = Vb + (size_t)t * 4096;
    bf16x8 va[2][4];
#pragma unroll
    for (int ksub = 0; ksub < 2; ++ksub)
#pragma unroll
      for (int df = 0; df < 4; ++df)
        va[ksub][df] = *(const bf16x8*)(Vt + (ksub * 4 + df) * 512 + lane * 8);
    __builtin_amdgcn_sched_barrier(0);

    const char* Ks = smem + 16384 + ((t & 1) << 13);
    f32x4 s[4];
#pragma unroll
    for (int nf = 0; nf < 4; ++nf) s[nf] = f32x4{0.f, 0.f, 0.f, 0.f};
    __builtin_amdgcn_s_setprio(1);
#pragma unroll
    for (int ksub = 0; ksub < 2; ++ksub) {
      int j16 = ksub * 4 + l4;
      bf16x8 kb[4];
#pragma unroll
      for (int nf = 0; nf < 4; ++nf) {
        int r = nf * 16 + l15;
        kb[nf] = *(const bf16x8*)(Ks + r * 128 + ((j16 ^ (r & 7)) * 16));
      }
#pragma unroll
      for (int nf = 0; nf < 4; ++nf) s[nf] = mfma16(kb[nf], qa[ksub], s[nf]);
    }
    __builtin_amdgcn_s_setprio(0);

    // p = 2^(s - c2) -> Pf32 LDS (fragment layout, swizzled chunks)
#pragma unroll
    for (int nf = 0; nf < 4; ++nf) {
      f32x4 p4;
#pragma unroll
      for (int r = 0; r < 4; ++r) p4[r] = exp2v(s[nf][r] - c2);
      *(f32x4*)(Pw + l15 * 256 + (((nf * 4 + l4) ^ swz) * 16)) = p4;
    }
    // transposed read -> full-line nontemporal global stores
#pragma unroll
    for (int j = 0; j < 4; ++j) {
      int row = 4 * j + (lane >> 4);
      f32x4 v = *(const f32x4*)(Pw + row * 256 + (((lane & 15) ^ (row & 7)) * 16));
      __builtin_nontemporal_store(
          v, (f32x4*)(awave + (size_t)row * L_ + c0 + (lane & 15) * 4));
    }
    // PV: rebuild pa from Pf32 (pairs -> bf16), accumulate with coalesced-V regs
    __builtin_amdgcn_s_setprio(1);
#pragma unroll
    for (int ksub = 0; ksub < 2; ++ksub) {
      int cbase = (ksub * 4 + l4) * 2;
      f32x4 plo = *(const f32x4*)(Pw + l15 * 256 + ((cbase ^ swz) * 16));
      f32x4 phi = *(const f32x4*)(Pw + l15 * 256 + (((cbase + 1) ^ swz) * 16));
      union { u32x4 u; bf16x8 h; } pa;
      pa.u[0] = pkbf(plo[0], plo[1]);
      pa.u[1] = pkbf(plo[2], plo[3]);
      pa.u[2] = pkbf(phi[0], phi[1]);
      pa.u[3] = pkbf(phi[2], phi[3]);
#pragma unroll
      for (int df = 0; df < 4; ++df)
        cacc[df] = mfma16(pa.h, va[ksub][df], cacc[df]);
    }
    __builtin_amdgcn_s_setprio(0);
    if (t < 31) {
      asm volatile("s_waitcnt vmcnt(12)" ::: "memory");
      __builtin_amdgcn_s_barrier();
      __builtin_amdgcn_sched_barrier(0);
    }
  }

  // ctx write (bf16): row = q0 + w*16 + 4*l4 + r, col = h*64 + df*16 + l15
#pragma unroll
  for (int df = 0; df < 4; ++df) {
#pragma unroll
    for (int r = 0; r < 4; ++r) {
      int row = q0 + w * 16 + l4 * 4 + r;
      int col = h * DH_ + df * 16 + l15;
      ctx[(size_t)(b * L_ + row) * D_MODEL_ + col] = f2bf(cacc[df][r]);
    }
  }
}

// ---------------------------------------------------------------- launch
extern "C" void kernel_launch(void* const* d_in, const int* in_sizes, int n_in,
                              void* d_out, int out_size, void* d_ws, size_t ws_size,
                              hipStream_t stream) {
  const float* q = (const float*)d_in[0];
  const float* k = (const float*)d_in[1];
  const float* v = (const float*)d_in[2];
  const float* w_q = (const float*)d_in[3];
  const float* b_q = (const float*)d_in[4];
  const float* w_k = (const float*)d_in[5];
  const float* b_k = (const float*)d_in[6];
  const float* w_v = (const float*)d_in[7];
  const float* b_v = (const float*)d_in[8];
  const float* w_o = (const float*)d_in[9];
  const float* b_o = (const float*)d_in[10];

  float* out = (float*)d_out;
  float* attn = (float*)d_out + (size_t)B_ * L_ * D_MODEL_;

  const size_t MB = 1u << 20;
  char* ws = (char*)d_ws;
  u16* qb = (u16*)(ws + 0 * MB);
  u16* kb = (u16*)(ws + 8 * MB);    // reused as ctx(bf16) after QKV GEMM
  u16* vb = (u16*)(ws + 16 * MB);
  u16* wqb = (u16*)(ws + 24 * MB);
  u16* wkb = (u16*)(ws + 26 * MB);
  u16* wvb = (u16*)(ws + 28 * MB);
  u16* wob = (u16*)(ws + 30 * MB);
  u16* Qp = (u16*)(ws + 32 * MB);
  u16* Kp = (u16*)(ws + 40 * MB);
  u16* VF = (u16*)(ws + 48 * MB);        // fragment-order V, 8MB
  float* sums = (float*)(ws + 56 * MB);  // B*H*L f32 = 256KB
  u16* ctx = kb;

  // 1. cast everything to bf16 (+ zero sums)
  CastArgs ca;
  ca.src[0] = q;   ca.dst[0] = qb;  ca.n8[0] = (B_ * L_ * D_MODEL_) / 8;
  ca.src[1] = k;   ca.dst[1] = kb;  ca.n8[1] = (B_ * L_ * D_MODEL_) / 8;
  ca.src[2] = v;   ca.dst[2] = vb;  ca.n8[2] = (B_ * L_ * D_MODEL_) / 8;
  ca.src[3] = w_q; ca.dst[3] = wqb; ca.n8[3] = (D_MODEL_ * D_MODEL_) / 8;
  ca.src[4] = w_k; ca.dst[4] = wkb; ca.n8[4] = (D_MODEL_ * D_MODEL_) / 8;
  ca.src[5] = w_v; ca.dst[5] = wvb; ca.n8[5] = (D_MODEL_ * D_MODEL_) / 8;
  ca.src[6] = w_o; ca.dst[6] = wob; ca.n8[6] = (D_MODEL_ * D_MODEL_) / 8;
  ca.src[7] = nullptr; ca.dst[7] = (u16*)sums; ca.n8[7] = (B_ * H_ * L_ * 4) / 16;
  cast_kernel<<<dim3(1024, 1, 8), 256, 0, stream>>>(ca);

  // 2. QKV projections. Q's alpha folds 1/8 (score scale) * log2(e) (base-2 exp domain).
  GemmArgs ga;
  ga.X[0] = qb;  ga.W[0] = wqb; ga.bias[0] = b_q; ga.out[0] = Qp; ga.alpha[0] = 0.125f * 1.44269504f; ga.mode[0] = 0;
  ga.X[1] = kb;  ga.W[1] = wkb; ga.bias[1] = b_k; ga.out[1] = Kp; ga.alpha[1] = 1.f;    ga.mode[1] = 0;
  ga.X[2] = vb;  ga.W[2] = wvb; ga.bias[2] = b_v; ga.out[2] = VF; ga.alpha[2] = 1.f;    ga.mode[2] = 2;
  gemm_bt<<<dim3(8, 32, 3), 256, 0, stream>>>(ga);

  // 3a. row sums of 2^(s-SHIFT2)
  sumexp_kernel<<<dim3(32, 4, 32), 256, 0, stream>>>(Qp, Kp, sums);

  // 3b. attention pass 2: coalesced fragment-order V + XCD-contiguous writes
  attn_kernel<<<dim3(1024, 1, 1), 256, 0, stream>>>(Qp, Kp, VF, sums, attn, ctx);

  // 4. output projection (f32 out + bias)
  GemmArgs go;
  go.X[0] = ctx; go.W[0] = wob; go.bias[0] = b_o; go.out[0] = out; go.alpha[0] = 1.f; go.mode[0] = 1;
  go.X[1] = ctx; go.W[1] = wob; go.bias[1] = b_o; go.out[1] = out; go.alpha[1] = 1.f; go.mode[1] = 1;
  go.X[2] = ctx; go.W[2] = wob; go.bias[2] = b_o; go.out[2] = out; go.alpha[2] = 1.f; go.mode[2] = 1;
  gemm_bt<<<dim3(8, 32, 1), 256, 0, stream>>>(go);
}

// Round 18
// 241.795 us; speedup vs baseline: 1.4211x; 1.0164x over previous
//
#include <hip/hip_runtime.h>
#include <hip/hip_bf16.h>
#include <stdint.h>

#define DEV static __device__ __forceinline__

typedef float f32x4 __attribute__((ext_vector_type(4)));
typedef __bf16 bf16x8 __attribute__((ext_vector_type(8)));
typedef unsigned short u16x8 __attribute__((ext_vector_type(8)));
typedef unsigned short u16x4 __attribute__((ext_vector_type(4)));
typedef uint32_t u32x4 __attribute__((ext_vector_type(4)));
typedef unsigned short u16;

#define B_ 2
#define L_ 2048
#define D_MODEL_ 1024
#define H_ 16
#define DH_ 64

// shift in base-2 score domain: 8 (base-e) * log2(e)
#define SHIFT2 11.5415603f

DEV u16 f2bf(float f) {
  union { float f; uint32_t u; } v; v.f = f;
  uint32_t r = v.u + 0x7FFFu + ((v.u >> 16) & 1u);  // RNE
  return (u16)(r >> 16);
}

DEV float exp2v(float x) {
#if __has_builtin(__builtin_amdgcn_exp2f)
  return __builtin_amdgcn_exp2f(x);
#else
  float r;
  asm("v_exp_f32 %0, %1" : "=v"(r) : "v"(x));
  return r;
#endif
}

// pack two f32 -> u32 of 2x bf16 (lo = a, hi = b), RNE
DEV uint32_t pkbf(float a, float b) {
  __hip_bfloat162 h = __float22bfloat162_rn(float2{a, b});
  union { __hip_bfloat162 h; uint32_t u; } cv; cv.h = h;
  return cv.u;
}

DEV f32x4 mfma16(bf16x8 a, bf16x8 b, f32x4 c) {
  return __builtin_amdgcn_mfma_f32_16x16x32_bf16(a, b, c, 0, 0, 0);
}

// async global->LDS, 16B per lane. LDS dest = wave-uniform base + lane*16.
DEV void gl_lds16(const void* g, void* l) {
  __builtin_amdgcn_global_load_lds(
      (const __attribute__((address_space(1))) unsigned int*)g,
      (__attribute__((address_space(3))) unsigned int*)l, 16, 0, 0);
}

// ---------------------------------------------------------------- cast f32->bf16 (src==null -> zero fill)
struct CastArgs {
  const float* src[8];
  u16* dst[8];
  int n8[8];
};

__global__ __launch_bounds__(256) void cast_kernel(CastArgs a) {
  const int z = blockIdx.z;
  u16* d = a.dst[z];
  const int n8 = a.n8[z];
  const int stride = gridDim.x * blockDim.x;
  const float* s = a.src[z];
  if (s == nullptr) {
    for (int i = blockIdx.x * blockDim.x + threadIdx.x; i < n8; i += stride)
      *((u16x8*)d + i) = u16x8{0, 0, 0, 0, 0, 0, 0, 0};
    return;
  }
  for (int i = blockIdx.x * blockDim.x + threadIdx.x; i < n8; i += stride) {
    const float4* sp = (const float4*)s + (size_t)i * 2;
    float4 x0 = sp[0], x1 = sp[1];
    u16x8 o;
    o[0] = f2bf(x0.x); o[1] = f2bf(x0.y); o[2] = f2bf(x0.z); o[3] = f2bf(x0.w);
    o[4] = f2bf(x1.x); o[5] = f2bf(x1.y); o[6] = f2bf(x1.z); o[7] = f2bf(x1.w);
    *((u16x8*)d + i) = o;
  }
}

// ---------------------------------------------------------------- GEMM  out = (X @ W^T + bias) * alpha
// mode 0: bf16 row-major out; mode 1: f32 row-major out
// mode 2: V fragment-order VF[bh][t][frag8][lane64][8] (bf16)
// mode 3: K fragment-order KF[bh][t][frag8][lane64][8] (bf16)
#define GM 4096
#define GN 1024
#define GK 1024

struct GemmArgs {
  const u16* X[3];
  const u16* W[3];
  const float* bias[3];
  void* out[3];
  float alpha[3];
  int mode[3];
};

__global__ __launch_bounds__(256) void gemm_bt(GemmArgs g) {
  const int z = blockIdx.z;
  const u16* X = g.X[z];
  const u16* W = g.W[z];
  const float* bias = g.bias[z];
  const float alpha = g.alpha[z];
  const int mode = g.mode[z];
  const int m0 = blockIdx.y * 128, n0 = blockIdx.x * 128;

  __shared__ __align__(16) char smem[32 * 1024];
  char* As = smem;            // [128 rows][128B] XOR-swizzled by ((r&7)<<4)
  char* Bs = smem + 16 * 1024;

  const int tid = threadIdx.x;
  const int lane = tid & 63, w = tid >> 6;
  const int l15 = lane & 15, l4 = lane >> 4;
  const int wm = (w >> 1) * 64, wn = (w & 1) * 64;

  f32x4 acc[4][4];
#pragma unroll
  for (int i = 0; i < 4; ++i)
#pragma unroll
    for (int j = 0; j < 4; ++j) acc[i][j] = f32x4{0.f, 0.f, 0.f, 0.f};

  for (int ks = 0; ks < GK; ks += 64) {
    __syncthreads();
    for (int c = w; c < 16; c += 4) {
      int r = c * 8 + (lane >> 3);
      int j = lane & 7;
      int sj = j ^ (r & 7);
      gl_lds16((const char*)(X + (size_t)(m0 + r) * GK + ks) + sj * 16, As + c * 1024);
      gl_lds16((const char*)(W + (size_t)(n0 + r) * GK + ks) + sj * 16, Bs + c * 1024);
    }
    __syncthreads();
#pragma unroll
    for (int ksub = 0; ksub < 2; ++ksub) {
      bf16x8 af[4], bfr[4];
#pragma unroll
      for (int mf = 0; mf < 4; ++mf) {
        int r = wm + mf * 16 + l15;
        int j16 = ksub * 4 + l4;
        af[mf] = *(const bf16x8*)(As + r * 128 + ((j16 ^ (r & 7)) * 16));
      }
#pragma unroll
      for (int nf = 0; nf < 4; ++nf) {
        int r = wn + nf * 16 + l15;
        int j16 = ksub * 4 + l4;
        bfr[nf] = *(const bf16x8*)(Bs + r * 128 + ((j16 ^ (r & 7)) * 16));
      }
#pragma unroll
      for (int mf = 0; mf < 4; ++mf)
#pragma unroll
        for (int nf = 0; nf < 4; ++nf) acc[mf][nf] = mfma16(af[mf], bfr[nf], acc[mf][nf]);
    }
  }

  if (mode == 2) {
    // V -> fragment-order VF: value (l = m&2047, dh = n&63)
    //   lane in pass2 = l4v*16+l15v with key-chunk c=(l&63)>>3 -> (c>>2)=ksub,(c&3)=l4v; l15v = dh&15? NO:
    //   VF frag: row df = (dh)>>4? -- layout as R17 (unchanged, verified)
    u16* base = (u16*)g.out[z];
#pragma unroll
    for (int nf = 0; nf < 4; ++nf) {
      int n = n0 + wn + nf * 16 + l15;
      float bv = bias[n];
      int df = (n & 63) >> 4, fl15 = n & 15, hh = n >> 6;
#pragma unroll
      for (int mf = 0; mf < 4; ++mf) {
        int m = m0 + wm + mf * 16 + l4 * 4;
        u16x4 pk;
#pragma unroll
        for (int r = 0; r < 4; ++r) pk[r] = f2bf((acc[mf][nf][r] + bv) * alpha);
        int lg = m & 2047, bb = m >> 11;
        int t = lg >> 6, lc = lg & 63;
        int c = lc >> 3, e = lc & 7;
        size_t off = ((((size_t)(bb * H_ + hh) * 32 + t) * 8 + (c >> 2) * 4 + df) * 512) +
                     ((c & 3) * 16 + fl15) * 8 + e;
        *(u16x4*)(base + off) = pk;
      }
    }
  } else if (mode == 3) {
    // K -> fragment-order KF: value (key l = m&2047, dh = n&63)
    //   frag = (dh>>3>>2)*4 + ((l>>4)&3); lane = ((dh>>3)&3)*16 + (l&15); e = dh&7
    u16* base = (u16*)g.out[z];
#pragma unroll
    for (int nf = 0; nf < 4; ++nf) {
      int n = n0 + wn + nf * 16 + l15;
      float bv = bias[n];
      int dh = n & 63, hh = n >> 6;
      int c = dh >> 3;
      int fragb = (c >> 2) * 4, laneb = (c & 3) * 16, e = dh & 7;
#pragma unroll
      for (int mf = 0; mf < 4; ++mf) {
#pragma unroll
        for (int r = 0; r < 4; ++r) {
          int m = m0 + wm + mf * 16 + l4 * 4 + r;
          int lg = m & 2047, bb = m >> 11;
          int t = lg >> 6, nfk = (lg >> 4) & 3, l15k = lg & 15;
          size_t off = ((((size_t)(bb * H_ + hh) * 32 + t) * 8 + fragb + nfk) * 512) +
                       (laneb + l15k) * 8 + e;
          base[off] = f2bf((acc[mf][nf][r] + bv) * alpha);
        }
      }
    }
  } else {
#pragma unroll
    for (int nf = 0; nf < 4; ++nf) {
      int n = n0 + wn + nf * 16 + l15;
      float bv = bias[n];
#pragma unroll
      for (int mf = 0; mf < 4; ++mf) {
#pragma unroll
        for (int r = 0; r < 4; ++r) {
          int m = m0 + wm + mf * 16 + l4 * 4 + r;
          float val = (acc[mf][nf][r] + bv) * alpha;
          if (mode == 1)
            ((float*)g.out[z])[(size_t)m * GN + n] = val;
          else
            ((u16*)g.out[z])[(size_t)m * GN + n] = f2bf(val);
        }
      }
    }
  }
}

// ---------------------------------------------------------------- sum-exp kernel (barrier-free, fragment K)
// sums[bh][row] += sum over 512-key chunk of 2^(s - SHIFT2).
__global__ __launch_bounds__(256) void sumexp_kernel(const u16* Qp, const u16* KF,
                                                     float* sums) {
  const int q0 = blockIdx.x * 64;
  const int tb = blockIdx.y * 8;  // first key tile of this block's 512-key chunk
  const int bh = blockIdx.z;
  const int b = bh >> 4, h = bh & 15;
  const int tid = threadIdx.x, lane = tid & 63, w = tid >> 6;
  const int l15 = lane & 15, l4 = lane >> 4;

  const u16* Qbase = Qp + ((size_t)(b * L_ + q0 + w * 16) * D_MODEL_ + h * DH_);
  const u16* Kf = KF + ((size_t)bh * 32) * 4096;

  bf16x8 qa[2];
#pragma unroll
  for (int ksub = 0; ksub < 2; ++ksub)
    qa[ksub] = *(const bf16x8*)(Qbase + (size_t)l15 * D_MODEL_ + (ksub * 4 + l4) * 8);

  float ssum = 0.f;
  for (int t = 0; t < 8; ++t) {
    const u16* Kt = Kf + (size_t)(tb + t) * 4096;
    f32x4 s[4];
#pragma unroll
    for (int nf = 0; nf < 4; ++nf) s[nf] = f32x4{0.f, 0.f, 0.f, 0.f};
    __builtin_amdgcn_s_setprio(1);
#pragma unroll
    for (int ksub = 0; ksub < 2; ++ksub) {
      bf16x8 kb[4];
#pragma unroll
      for (int nf = 0; nf < 4; ++nf)
        kb[nf] = *(const bf16x8*)(Kt + (ksub * 4 + nf) * 512 + lane * 8);
#pragma unroll
      for (int nf = 0; nf < 4; ++nf) s[nf] = mfma16(kb[nf], qa[ksub], s[nf]);
    }
    __builtin_amdgcn_s_setprio(0);
#pragma unroll
    for (int nf = 0; nf < 4; ++nf)
#pragma unroll
      for (int r = 0; r < 4; ++r) ssum += exp2v(s[nf][r] - SHIFT2);
  }

  // merge the 4 l4-groups (different dh-chunks contributed zero; keys split over l4? no —
  // swapped QK^T: lane owns q-row l15; l4 spans key sub-ranges within fragments)
  ssum += __shfl_xor(ssum, 16);
  ssum += __shfl_xor(ssum, 32);
  if (lane < 16)
    atomicAdd(&sums[((size_t)bh << 11) + q0 + w * 16 + lane], ssum);
}

// ---------------------------------------------------------------- attention pass 2 (barrier-free)
// K AND V in fragment order: every operand load is 64 lanes x 16B contiguous
// (1KB / 8 lines per instruction). No LDS staging, no barriers — 4
// independent waves/block, LDS = wave-private Pf32 only (16KB). NT
// transposed P stores; XCD-contiguous write spans.
__global__ __launch_bounds__(256) void attn_kernel(const u16* Qp, const u16* KF,
                                                   const u16* VF, const float* sums,
                                                   float* attn, u16* ctx) {
  const int bid = blockIdx.x;
  const int lid = (bid & 7) * 128 + (bid >> 3);  // bijective: 1024 % 8 == 0
  const int q0 = (lid & 31) * 64;
  const int h = (lid >> 5) & 15;
  const int b = lid >> 9;
  const int tid = threadIdx.x, lane = tid & 63, w = tid >> 6;
  const int l15 = lane & 15, l4 = lane >> 4;

  __shared__ __align__(16) char smem[16 * 1024];  // Pf32 per wave
  char* Pw = smem + w * 4096;

  const u16* Qbase = Qp + ((size_t)(b * L_ + q0 + w * 16) * D_MODEL_ + h * DH_);
  const u16* Kf = KF + ((size_t)(b * H_ + h) * 32) * 4096;
  const u16* Vb = VF + ((size_t)(b * H_ + h) * 32) * 4096;
  float* attnb = attn + ((size_t)(b * H_ + h)) * L_ * L_;

  bf16x8 qa[2];
#pragma unroll
  for (int ksub = 0; ksub < 2; ++ksub)
    qa[ksub] = *(const bf16x8*)(Qbase + (size_t)l15 * D_MODEL_ + (ksub * 4 + l4) * 8);

  // per-lane normalizer from precomputed sums (lane's q-row = l15)
  const float c2 =
      SHIFT2 + __log2f(sums[(((size_t)(b * H_ + h)) << 11) + q0 + w * 16 + l15]);

  f32x4 cacc[4];
#pragma unroll
  for (int i = 0; i < 4; ++i) cacc[i] = f32x4{0.f, 0.f, 0.f, 0.f};

  const int swz = l15 & 7;
  float* awave = attnb + (size_t)(q0 + w * 16) * L_;

  for (int t = 0; t < 32; ++t) {
    const int c0 = t * 64;
    const u16* Kt = Kf + (size_t)t * 4096;
    const u16* Vt = Vb + (size_t)t * 4096;
    // coalesced fragment loads (1KB each)
    bf16x8 kb[2][4], va[2][4];
#pragma unroll
    for (int ksub = 0; ksub < 2; ++ksub)
#pragma unroll
      for (int i = 0; i < 4; ++i) {
        kb[ksub][i] = *(const bf16x8*)(Kt + (ksub * 4 + i) * 512 + lane * 8);
        va[ksub][i] = *(const bf16x8*)(Vt + (ksub * 4 + i) * 512 + lane * 8);
      }

    f32x4 s[4];
#pragma unroll
    for (int nf = 0; nf < 4; ++nf) s[nf] = f32x4{0.f, 0.f, 0.f, 0.f};
    __builtin_amdgcn_s_setprio(1);
#pragma unroll
    for (int ksub = 0; ksub < 2; ++ksub)
#pragma unroll
      for (int nf = 0; nf < 4; ++nf) s[nf] = mfma16(kb[ksub][nf], qa[ksub], s[nf]);
    __builtin_amdgcn_s_setprio(0);

    // p = 2^(s - c2) -> Pf32 LDS (wave-private, in-order DS)
#pragma unroll
    for (int nf = 0; nf < 4; ++nf) {
      f32x4 p4;
#pragma unroll
      for (int r = 0; r < 4; ++r) p4[r] = exp2v(s[nf][r] - c2);
      *(f32x4*)(Pw + l15 * 256 + (((nf * 4 + l4) ^ swz) * 16)) = p4;
    }
    // transposed read -> full-line nontemporal global stores
#pragma unroll
    for (int j = 0; j < 4; ++j) {
      int row = 4 * j + (lane >> 4);
      f32x4 v = *(const f32x4*)(Pw + row * 256 + (((lane & 15) ^ (row & 7)) * 16));
      __builtin_nontemporal_store(
          v, (f32x4*)(awave + (size_t)row * L_ + c0 + (lane & 15) * 4));
    }
    // PV: rebuild pa from Pf32 (pairs -> bf16), accumulate with coalesced-V regs
    __builtin_amdgcn_s_setprio(1);
#pragma unroll
    for (int ksub = 0; ksub < 2; ++ksub) {
      int cbase = (ksub * 4 + l4) * 2;
      f32x4 plo = *(const f32x4*)(Pw + l15 * 256 + ((cbase ^ swz) * 16));
      f32x4 phi = *(const f32x4*)(Pw + l15 * 256 + (((cbase + 1) ^ swz) * 16));
      union { u32x4 u; bf16x8 h; } pa;
      pa.u[0] = pkbf(plo[0], plo[1]);
      pa.u[1] = pkbf(plo[2], plo[3]);
      pa.u[2] = pkbf(phi[0], phi[1]);
      pa.u[3] = pkbf(phi[2], phi[3]);
#pragma unroll
      for (int df = 0; df < 4; ++df)
        cacc[df] = mfma16(pa.h, va[ksub][df], cacc[df]);
    }
    __builtin_amdgcn_s_setprio(0);
  }

  // ctx write (bf16): row = q0 + w*16 + 4*l4 + r, col = h*64 + df*16 + l15
#pragma unroll
  for (int df = 0; df < 4; ++df) {
#pragma unroll
    for (int r = 0; r < 4; ++r) {
      int row = q0 + w * 16 + l4 * 4 + r;
      int col = h * DH_ + df * 16 + l15;
      ctx[(size_t)(b * L_ + row) * D_MODEL_ + col] = f2bf(cacc[df][r]);
    }
  }
}

// ---------------------------------------------------------------- launch
extern "C" void kernel_launch(void* const* d_in, const int* in_sizes, int n_in,
                              void* d_out, int out_size, void* d_ws, size_t ws_size,
                              hipStream_t stream) {
  const float* q = (const float*)d_in[0];
  const float* k = (const float*)d_in[1];
  const float* v = (const float*)d_in[2];
  const float* w_q = (const float*)d_in[3];
  const float* b_q = (const float*)d_in[4];
  const float* w_k = (const float*)d_in[5];
  const float* b_k = (const float*)d_in[6];
  const float* w_v = (const float*)d_in[7];
  const float* b_v = (const float*)d_in[8];
  const float* w_o = (const float*)d_in[9];
  const float* b_o = (const float*)d_in[10];

  float* out = (float*)d_out;
  float* attn = (float*)d_out + (size_t)B_ * L_ * D_MODEL_;

  const size_t MB = 1u << 20;
  char* ws = (char*)d_ws;
  u16* qb = (u16*)(ws + 0 * MB);
  u16* kb = (u16*)(ws + 8 * MB);    // reused as ctx(bf16) after QKV GEMM
  u16* vb = (u16*)(ws + 16 * MB);
  u16* wqb = (u16*)(ws + 24 * MB);
  u16* wkb = (u16*)(ws + 26 * MB);
  u16* wvb = (u16*)(ws + 28 * MB);
  u16* wob = (u16*)(ws + 30 * MB);
  u16* Qp = (u16*)(ws + 32 * MB);
  u16* KF = (u16*)(ws + 40 * MB);        // fragment-order K, 8MB
  u16* VF = (u16*)(ws + 48 * MB);        // fragment-order V, 8MB
  float* sums = (float*)(ws + 56 * MB);  // B*H*L f32 = 256KB
  u16* ctx = kb;

  // 1. cast everything to bf16 (+ zero sums)
  CastArgs ca;
  ca.src[0] = q;   ca.dst[0] = qb;  ca.n8[0] = (B_ * L_ * D_MODEL_) / 8;
  ca.src[1] = k;   ca.dst[1] = kb;  ca.n8[1] = (B_ * L_ * D_MODEL_) / 8;
  ca.src[2] = v;   ca.dst[2] = vb;  ca.n8[2] = (B_ * L_ * D_MODEL_) / 8;
  ca.src[3] = w_q; ca.dst[3] = wqb; ca.n8[3] = (D_MODEL_ * D_MODEL_) / 8;
  ca.src[4] = w_k; ca.dst[4] = wkb; ca.n8[4] = (D_MODEL_ * D_MODEL_) / 8;
  ca.src[5] = w_v; ca.dst[5] = wvb; ca.n8[5] = (D_MODEL_ * D_MODEL_) / 8;
  ca.src[6] = w_o; ca.dst[6] = wob; ca.n8[6] = (D_MODEL_ * D_MODEL_) / 8;
  ca.src[7] = nullptr; ca.dst[7] = (u16*)sums; ca.n8[7] = (B_ * H_ * L_ * 4) / 16;
  cast_kernel<<<dim3(1024, 1, 8), 256, 0, stream>>>(ca);

  // 2. QKV projections. Q row-major; K,V fragment-order.
  GemmArgs ga;
  ga.X[0] = qb;  ga.W[0] = wqb; ga.bias[0] = b_q; ga.out[0] = Qp; ga.alpha[0] = 0.125f * 1.44269504f; ga.mode[0] = 0;
  ga.X[1] = kb;  ga.W[1] = wkb; ga.bias[1] = b_k; ga.out[1] = KF; ga.alpha[1] = 1.f;    ga.mode[1] = 3;
  ga.X[2] = vb;  ga.W[2] = wvb; ga.bias[2] = b_v; ga.out[2] = VF; ga.alpha[2] = 1.f;    ga.mode[2] = 2;
  gemm_bt<<<dim3(8, 32, 3), 256, 0, stream>>>(ga);

  // 3a. row sums of 2^(s-SHIFT2): barrier-free fragment-K
  sumexp_kernel<<<dim3(32, 4, 32), 256, 0, stream>>>(Qp, KF, sums);

  // 3b. attention pass 2: barrier-free, all-fragment operands
  attn_kernel<<<dim3(1024, 1, 1), 256, 0, stream>>>(Qp, KF, VF, sums, attn, ctx);

  // 4. output projection (f32 out + bias)
  GemmArgs go;
  go.X[0] = ctx; go.W[0] = wob; go.bias[0] = b_o; go.out[0] = out; go.alpha[0] = 1.f; go.mode[0] = 1;
  go.X[1] = ctx; go.W[1] = wob; go.bias[1] = b_o; go.out[1] = out; go.alpha[1] = 1.f; go.mode[1] = 1;
  go.X[2] = ctx; go.W[2] = wob; go.bias[2] = b_o; go.out[2] = out; go.alpha[2] = 1.f; go.mode[2] = 1;
  gemm_bt<<<dim3(8, 32, 1), 256, 0, stream>>>(go);
}